// Round 7
// baseline (740.643 us; speedup 1.0000x reference)
//
#include <hip/hip_runtime.h>
#include <math.h>

// completeNet: graph-net + Sinkhorn. 3 mega-kernels with intra-kernel
// flag-based dataflow (all stages co-resident -> spin-waits are deadlock-free).
// T=256 tracks (nodes 0..255), M=256 dets (nodes 256..511), D_IN=512, D_EMB=256.

__device__ __forceinline__ float sigmoidf_(float x) { return 1.0f / (1.0f + expf(-x)); }

typedef _Float16 h2t __attribute__((ext_vector_type(2)));

__device__ __forceinline__ h2t pack2(float x, float y) {
  h2t r; r.x = (_Float16)x; r.y = (_Float16)y; return r;
}
__device__ __forceinline__ float fdot2f(h2t a, h2t b, float c) {
  return __builtin_amdgcn_fdot2(a, b, c, false);
}
template <int CTRL>
__device__ __forceinline__ float dpp_get(float x) {
  return __builtin_bit_cast(
      float, __builtin_amdgcn_mov_dpp(__builtin_bit_cast(int, x), CTRL, 0xF, 0xF, false));
}
template <int IMM>
__device__ __forceinline__ float swz_get(float x) {
  return __builtin_bit_cast(
      float, __builtin_amdgcn_ds_swizzle(__builtin_bit_cast(int, x), IMM));
}
__device__ __forceinline__ float allred16(float x) {
  x += dpp_get<0xB1>(x);   // xor1
  x += dpp_get<0x4E>(x);   // xor2
  x += dpp_get<0x141>(x);  // xor7
  x += dpp_get<0x140>(x);  // xor15
  return x;
}

// Producer/consumer flags (agent scope; pattern HW-validated in round 1).
__device__ __forceinline__ void signal_flag(unsigned* f) {
  __syncthreads();                       // drains each thread's stores (vmcnt 0)
  if (threadIdx.x == 0) {
    __threadfence();                     // publish block's stores agent-wide
    __hip_atomic_fetch_add(f, 1u, __ATOMIC_ACQ_REL, __HIP_MEMORY_SCOPE_AGENT);
  }
}
__device__ __forceinline__ void wait_flag(const unsigned* f, unsigned target) {
  if (threadIdx.x == 0) {
    while (__hip_atomic_load(f, __ATOMIC_ACQUIRE, __HIP_MEMORY_SCOPE_AGENT) < target)
      __builtin_amdgcn_s_sleep(1);
    __threadfence();                     // invalidate stale caches
  }
  __syncthreads();
}

// ===========================================================================
// MEGA1: blocks 0..127 = h = relu(x@Wc+bc) tiles; blocks 128..383 = PQG tiles.
// PQG[:, :128]=P (+bapp1), [:,128:256]=Q, [:,256:]=G=h@Wo2.
// k2-tiles spin on per-row-block flags (8 k1 tiles per 32-row block).
__global__ __launch_bounds__(256, 2)
void mega1(const float* __restrict__ x, const float* __restrict__ Wc,
           const float* __restrict__ bc, float* __restrict__ h,
           const float* __restrict__ W1, const float* __restrict__ b1,
           const float* __restrict__ Wo2, float* __restrict__ PQG,
           unsigned* __restrict__ rowflag) {
  __shared__ __align__(16) float Ast[2][32][36];
  const int tid = threadIdx.x;
  const int tx = tid & 31, ty = tid >> 5;
  const int ar = tid >> 3, ac = (tid & 7) * 4;
  float4 aA, aB;
  float bA[32], bB[32];
  float acc[4] = {0.f, 0.f, 0.f, 0.f};

  if (blockIdx.x < 128) {  // ---------------- h-GEMM tile
    const int b = blockIdx.x;
    const int bm = (b >> 3) * 32, bn = (b & 7) * 32;
    const float* __restrict__ Bp = Wc + bn + tx;
    const float* __restrict__ Ap = x + (bm + ar) * 512 + ac;
#define M1A_LOAD(T, AREG, BARR)                                        \
    {                                                                  \
      AREG = *reinterpret_cast<const float4*>(Ap + (T) * 32);          \
      _Pragma("unroll") for (int kk = 0; kk < 32; ++kk)                \
          BARR[kk] = Bp[((T) * 32 + kk) * 256];                        \
    }
#define M1_STORE(BUF, AREG)                                            \
    {                                                                  \
      Ast[BUF][ac + 0][ar] = AREG.x; Ast[BUF][ac + 1][ar] = AREG.y;    \
      Ast[BUF][ac + 2][ar] = AREG.z; Ast[BUF][ac + 3][ar] = AREG.w;    \
    }
#define M1_COMP(BUF, BARR)                                             \
    {                                                                  \
      _Pragma("unroll") for (int kk = 0; kk < 32; ++kk) {              \
        const float4 a4 =                                              \
            *reinterpret_cast<const float4*>(&Ast[BUF][kk][4 * ty]);   \
        const float bv = BARR[kk];                                     \
        acc[0] = fmaf(a4.x, bv, acc[0]); acc[1] = fmaf(a4.y, bv, acc[1]); \
        acc[2] = fmaf(a4.z, bv, acc[2]); acc[3] = fmaf(a4.w, bv, acc[3]); \
      }                                                                \
    }
    M1A_LOAD(0, aA, bA);
    M1_STORE(0, aA);
    __syncthreads();
    for (int t = 0; t < 16; t += 2) {
      M1A_LOAD(t + 1, aB, bB);
      M1_COMP(0, bA);
      M1_STORE(1, aB);
      __syncthreads();
      if (t + 2 < 16) { M1A_LOAD(t + 2, aA, bA); }
      M1_COMP(1, bB);
      if (t + 2 < 16) { M1_STORE(0, aA); }
      __syncthreads();
    }
    const float bias = bc[bn + tx];
#pragma unroll
    for (int i = 0; i < 4; ++i) {
      const float vv = acc[i] + bias;
      h[(bm + 4 * ty + i) * 256 + bn + tx] = vv > 0.f ? vv : 0.f;
    }
    signal_flag(&rowflag[bm >> 5]);
#undef M1A_LOAD
  } else {  // ---------------- PQG tile
    const int b2 = blockIdx.x - 128;
    const int bm = (b2 >> 4) * 32, bn = (b2 & 15) * 32;
    const int col = bn + tx;
    const float* __restrict__ Bp;
    int ldb;
    if (bn < 128)      { Bp = W1 + col; ldb = 128; }
    else if (bn < 256) { Bp = W1 + 256 * 128 + (col - 128); ldb = 128; }
    else               { Bp = Wo2 + (col - 256); ldb = 256; }
    const float* __restrict__ Ap = h + (bm + ar) * 256 + ac;
    wait_flag(&rowflag[bm >> 5], 8);
#define M1B_LOAD(T, AREG, BARR)                                        \
    {                                                                  \
      AREG = *reinterpret_cast<const float4*>(Ap + (T) * 32);          \
      _Pragma("unroll") for (int kk = 0; kk < 32; ++kk)                \
          BARR[kk] = Bp[((T) * 32 + kk) * ldb];                        \
    }
    M1B_LOAD(0, aA, bA);
    M1_STORE(0, aA);
    __syncthreads();
    for (int t = 0; t < 8; t += 2) {
      M1B_LOAD(t + 1, aB, bB);
      M1_COMP(0, bA);
      M1_STORE(1, aB);
      __syncthreads();
      if (t + 2 < 8) { M1B_LOAD(t + 2, aA, bA); }
      M1_COMP(1, bB);
      if (t + 2 < 8) { M1_STORE(0, aA); }
      __syncthreads();
    }
    const float bias = (bn < 128) ? b1[col] : 0.f;
#pragma unroll
    for (int i = 0; i < 4; ++i)
      PQG[(bm + 4 * ty + i) * 512 + col] = acc[i] + bias;
#undef M1B_LOAD
#undef M1_STORE
#undef M1_COMP
  }
}

// ===========================================================================
// MEGA2: blocks 0..255 = edge block fr (BOTH directions, det rows chunked
// through LDS -> coalesced); blocks 256..383 = out-GEMM tiles (phase A h@Wo1
// immediately, spin on edge counter, then phase B E@G).
__global__ __launch_bounds__(256, 2)
void mega2(const float* __restrict__ PQG, const float* __restrict__ coords,
           const float* __restrict__ co, const float* __restrict__ Wapp2,
           const float* __restrict__ bapp2, const float* __restrict__ Wg1,
           const float* __restrict__ bg1, const float* __restrict__ Wg2,
           const float* __restrict__ bg2, const float* __restrict__ Wa1,
           const float* __restrict__ ba1, const float* __restrict__ Wa2,
           const float* __restrict__ ba2, float* __restrict__ E1,
           float* __restrict__ E2, float* __restrict__ iou1,
           const float* __restrict__ hgl, const float* __restrict__ Wo1,
           const float* __restrict__ bo, float* __restrict__ outm,
           unsigned* __restrict__ edgeflag) {
  __shared__ __align__(16) float Qs[256][33];   // 33 KB chunk staging
  __shared__ __align__(16) float sP[128], sQ[128], sW2[128];
  __shared__ __align__(16) float sWg1[256], sWg2[32], sGfix0[32], sGfix1[32];
  __shared__ float sWa1[16], sBa1[8], sWa2[8];
  __shared__ __align__(16) float Ast[2][32][36];
  const int tid = threadIdx.x;

  if (blockIdx.x < 256) {  // ---------------- edges for track fr, both dirs
    const int fr = blockIdx.x;
    if (tid < 128) {
      sP[tid] = PQG[fr * 512 + tid];
      sQ[tid] = PQG[fr * 512 + 128 + tid];
      sW2[tid] = Wapp2[tid];
    }
    sWg1[tid] = Wg1[tid];
    if (tid < 32) sWg2[tid] = Wg2[tid];
    if (tid < 16) sWa1[tid] = Wa1[tid];
    if (tid < 8) { sBa1[tid] = ba1[tid]; sWa2[tid] = Wa2[tid]; }
    __syncthreads();
    if (tid < 32) {
      float g0 = bg1[tid], g1 = g0;
#pragma unroll
      for (int q = 0; q < 4; ++q) {
        const float c = coords[fr * 4 + q];
        g0 = fmaf(c, sWg1[q * 32 + tid], g0);        // fr as src (E1)
        g1 = fmaf(c, sWg1[(4 + q) * 32 + tid], g1);  // fr as dst (E2)
      }
      sGfix0[tid] = g0;
      sGfix1[tid] = g1;
    }
    __syncthreads();

    const int d = tid;
    const int srow = tid >> 3, scq = (tid & 7) * 4;  // staging: 8 rows/pass
    float z0 = 0.f, z1 = 0.f;
    for (int c8 = 0; c8 < 8; ++c8) {
      const int j0 = c8 * 32;
#pragma unroll
      for (int k = 0; k < 8; ++k) {
        const int r = k * 32 + srow;
        const float4 v = *reinterpret_cast<const float4*>(
            &PQG[(256 + r) * 512 + j0 + scq]);
        Qs[r][scq + 0] = v.x; Qs[r][scq + 1] = v.y;
        Qs[r][scq + 2] = v.z; Qs[r][scq + 3] = v.w;
      }
      __syncthreads();
      if (j0 < 128) {  // cols = P[d] -> z1 pairs with Q[fr]
#pragma unroll
        for (int j = 0; j < 32; ++j) {
          const int jj = j0 + j;
          float a = sQ[jj] + Qs[d][j];
          a = a > 0.f ? a : 0.f;
          z1 = fmaf(a, sW2[jj], z1);
        }
      } else {         // cols = Q[d] -> z0 pairs with P[fr]
#pragma unroll
        for (int j = 0; j < 32; ++j) {
          const int jj = j0 + j - 128;
          float a = sP[jj] + Qs[d][j];
          a = a > 0.f ? a : 0.f;
          z0 = fmaf(a, sW2[jj], z0);
        }
      }
      __syncthreads();
    }
    const float app0 = sigmoidf_(z0 + bapp2[0]);
    const float app1 = sigmoidf_(z1 + bapp2[0]);
    // geo both directions
    const float4 cp = *reinterpret_cast<const float4*>(coords + (256 + d) * 4);
    float gz0 = 0.f, gz1 = 0.f;
#pragma unroll
    for (int m = 0; m < 32; ++m) {
      float h0 = sGfix0[m];  // det in dst slot (rows 4..7)
      h0 = fmaf(cp.x, sWg1[(4 + 0) * 32 + m], h0);
      h0 = fmaf(cp.y, sWg1[(4 + 1) * 32 + m], h0);
      h0 = fmaf(cp.z, sWg1[(4 + 2) * 32 + m], h0);
      h0 = fmaf(cp.w, sWg1[(4 + 3) * 32 + m], h0);
      h0 = h0 > 0.f ? h0 : 0.f;
      gz0 = fmaf(h0, sWg2[m], gz0);
      float h1 = sGfix1[m];  // det in src slot (rows 0..3)
      h1 = fmaf(cp.x, sWg1[0 * 32 + m], h1);
      h1 = fmaf(cp.y, sWg1[1 * 32 + m], h1);
      h1 = fmaf(cp.z, sWg1[2 * 32 + m], h1);
      h1 = fmaf(cp.w, sWg1[3 * 32 + m], h1);
      h1 = h1 > 0.f ? h1 : 0.f;
      gz1 = fmaf(h1, sWg2[m], gz1);
    }
    const float geo0 = sigmoidf_(gz0 + bg2[0]);
    const float geo1 = sigmoidf_(gz1 + bg2[0]);
    float ez0 = 0.f, ez1 = 0.f;
#pragma unroll
    for (int m = 0; m < 8; ++m) {
      float h0 = fmaf(app0, sWa1[m], fmaf(geo0, sWa1[8 + m], sBa1[m]));
      h0 = h0 > 0.f ? h0 : 0.f;
      ez0 = fmaf(h0, sWa2[m], ez0);
      float h1 = fmaf(app1, sWa1[m], fmaf(geo1, sWa1[8 + m], sBa1[m]));
      h1 = h1 > 0.f ? h1 : 0.f;
      ez1 = fmaf(h1, sWa2[m], ez1);
    }
    E1[fr * 256 + d] = sigmoidf_(ez0 + ba2[0]);
    E2[fr * 256 + d] = sigmoidf_(ez1 + ba2[0]);
    const float4 A4 = *reinterpret_cast<const float4*>(co + fr * 4);
    const float4 B4 = *reinterpret_cast<const float4*>(co + (256 + d) * 4);
    const float ix1 = fmaxf(A4.x, B4.x), iy1 = fmaxf(A4.y, B4.y);
    const float ix2 = fminf(A4.z, B4.z), iy2 = fminf(A4.w, B4.w);
    const float inter = fmaxf(ix2 - ix1, 0.f) * fmaxf(iy2 - iy1, 0.f);
    const float areaA = (A4.z - A4.x) * (A4.w - A4.y);
    const float areaB = (B4.z - B4.x) * (B4.w - B4.y);
    iou1[fr * 256 + d] = inter / (areaA + areaB - inter + 1e-8f);
    signal_flag(edgeflag);
  } else {  // ---------------- out-GEMM tile
    const int b5 = blockIdx.x - 256;
    const int tx = tid & 31, ty = tid >> 5;
    const int ar = tid >> 3, ac = (tid & 7) * 4;
    const int bm = (b5 >> 3) * 32, bn = (b5 & 7) * 32;
    const int col = bn + tx;
    const bool detrows = (bm >= 256);
    const float* __restrict__ Ap1 = hgl + (bm + ar) * 256 + ac;
    const float* __restrict__ Bp1 = Wo1 + col;
    const float* __restrict__ Ap2 = detrows
        ? (E1 + ar * 256 + (bm - 256) + ac)
        : (E2 + (bm + ar) * 256 + ac);
    const float* __restrict__ Bp2 = PQG + (detrows ? 0 : 256 * 512) + 256 + col;
    float4 aA, aB;
    float bA[32], bB[32];
    float acc[4] = {0.f, 0.f, 0.f, 0.f};

#define M2_STORE_T(BUF, AREG)                                          \
    {                                                                  \
      Ast[BUF][ac + 0][ar] = AREG.x; Ast[BUF][ac + 1][ar] = AREG.y;    \
      Ast[BUF][ac + 2][ar] = AREG.z; Ast[BUF][ac + 3][ar] = AREG.w;    \
    }
#define M2_STORE_D(BUF, AREG)                                          \
    { *reinterpret_cast<float4*>(&Ast[BUF][ar][ac]) = AREG; }
#define M2_COMP(BUF, BARR)                                             \
    {                                                                  \
      _Pragma("unroll") for (int kk = 0; kk < 32; ++kk) {              \
        const float4 a4 =                                              \
            *reinterpret_cast<const float4*>(&Ast[BUF][kk][4 * ty]);   \
        const float bv = BARR[kk];                                     \
        acc[0] = fmaf(a4.x, bv, acc[0]); acc[1] = fmaf(a4.y, bv, acc[1]); \
        acc[2] = fmaf(a4.z, bv, acc[2]); acc[3] = fmaf(a4.w, bv, acc[3]); \
      }                                                                \
    }
#define M2A_LOAD(T, AREG, BARR)                                        \
    {                                                                  \
      AREG = *reinterpret_cast<const float4*>(Ap1 + (T) * 32);         \
      _Pragma("unroll") for (int kk = 0; kk < 32; ++kk)                \
          BARR[kk] = Bp1[((T) * 32 + kk) * 256];                       \
    }
#define M2B_LOAD(T, AREG, BARR)                                        \
    {                                                                  \
      AREG = *reinterpret_cast<const float4*>(                         \
          Ap2 + (T) * 32 * (detrows ? 256 : 1));                       \
      _Pragma("unroll") for (int kk = 0; kk < 32; ++kk)                \
          BARR[kk] = Bp2[((T) * 32 + kk) * 512];                       \
    }
    // phase A: h @ Wo1 (no dependency on edges)
    M2A_LOAD(0, aA, bA);
    M2_STORE_T(0, aA);
    __syncthreads();
    for (int t = 0; t < 8; t += 2) {
      M2A_LOAD(t + 1, aB, bB);
      M2_COMP(0, bA);
      M2_STORE_T(1, aB);
      __syncthreads();
      if (t + 2 < 8) { M2A_LOAD(t + 2, aA, bA); }
      M2_COMP(1, bB);
      if (t + 2 < 8) { M2_STORE_T(0, aA); }
      __syncthreads();
    }
    // phase B: E @ G — wait for all 256 edge blocks
    wait_flag(edgeflag, 256);
    M2B_LOAD(0, aA, bA);
    if (detrows) { M2_STORE_D(0, aA); } else { M2_STORE_T(0, aA); }
    __syncthreads();
    for (int t = 0; t < 8; t += 2) {
      M2B_LOAD(t + 1, aB, bB);
      M2_COMP(0, bA);
      if (detrows) { M2_STORE_D(1, aB); } else { M2_STORE_T(1, aB); }
      __syncthreads();
      if (t + 2 < 8) { M2B_LOAD(t + 2, aA, bA); }
      M2_COMP(1, bB);
      if (t + 2 < 8) {
        if (detrows) { M2_STORE_D(0, aA); } else { M2_STORE_T(0, aA); }
      }
      __syncthreads();
    }
    const float bias = bo[col];
#pragma unroll
    for (int i = 0; i < 4; ++i) {
      const float vv = acc[i] + bias;
      outm[(bm + 4 * ty + i) * 256 + col] = vv > 0.f ? vv : 0.f;
    }
#undef M2_STORE_T
#undef M2_STORE_D
#undef M2_COMP
#undef M2A_LOAD
#undef M2B_LOAD
  }
}

// ===========================================================================
// MEGA3: blocks 0..63 = score (4 track rows/block, det rows chunk-staged in
// LDS shared by the 4 teams); block 64 = Sinkhorn (spins on score counter).
__global__ __launch_bounds__(1024)
void mega3(const float* __restrict__ outm, const float* __restrict__ iou1,
           const float* __restrict__ Wf1, const float* __restrict__ bf1,
           const float* __restrict__ Wf2, const float* __restrict__ bf2,
           float* __restrict__ Mblk, float* __restrict__ outp,
           unsigned* __restrict__ scoreflag) {
  __shared__ __align__(16) float so[4][260];
  __shared__ __align__(16) float ods[256][33];
  __shared__ __align__(16) float su_f[256];
  __shared__ __align__(16) float svs_f[256];
  __shared__ __align__(16) float psum[16][260];
  __shared__ float wsumU[16], wsumV[4];
  const int tid = threadIdx.x;

  if (blockIdx.x < 64) {  // ---------------- score
    const int team = tid >> 8, d = tid & 255;
    const int s = blockIdx.x * 4 + team;
    so[team][d] = outm[blockIdx.x * 1024 + tid];  // = outm[s*256+d], coalesced
    __syncthreads();
    const int srow0 = tid >> 3, scq = 4 * ((tid >> 1) & 3) * 2 + 0;  // unused helper
    (void)scq;
    float dot = 0.f, na2 = 0.f, nb2 = 0.f;
    for (int c8 = 0; c8 < 8; ++c8) {
      const int j0 = c8 * 32;
#pragma unroll
      for (int k = 0; k < 2; ++k) {
        const int qi = k * 1024 + tid;
        const int r = qi >> 3, cq = 4 * (qi & 7);
        const float4 v = *reinterpret_cast<const float4*>(
            &outm[(256 + r) * 256 + j0 + cq]);
        ods[r][cq + 0] = v.x; ods[r][cq + 1] = v.y;
        ods[r][cq + 2] = v.z; ods[r][cq + 3] = v.w;
      }
      __syncthreads();
#pragma unroll
      for (int j = 0; j < 32; ++j) {
        const float ov = ods[d][j];
        const float sv = so[team][j0 + j];
        dot = fmaf(sv, ov, dot);
        na2 = fmaf(sv, sv, na2);
        nb2 = fmaf(ov, ov, nb2);
      }
      __syncthreads();
    }
    (void)srow0;
    const float na = fmaxf(sqrtf(na2), 1e-6f);
    const float nb = fmaxf(sqrtf(nb2), 1e-6f);
    const float cosv = dot / (na * nb);
    const float i1 = iou1[s * 256 + d];
    float sz = 0.f;
#pragma unroll
    for (int m = 0; m < 8; ++m) {
      float hm = fmaf(cosv, Wf1[m], fmaf(i1, Wf1[8 + m], bf1[m]));
      hm = hm > 0.f ? hm : 0.f;
      sz = fmaf(hm, Wf2[m], sz);
    }
    const float score = sigmoidf_(sz + bf2[0]);
    Mblk[s * 256 + d] = expf(5.0f * score);
    signal_flag(scoreflag);
  } else {  // ---------------- Sinkhorn (single block)
    wait_flag(scoreflag, 64);
    const int w = tid >> 6, l = tid & 63;
    const float slack = 2.71828182845904523536f;  // exp(LAM*SLACK) = exp(1)
    const float INV256 = 0.00390625f;
    const int rev = ((l & 1) << 3) | ((l & 2) << 1) | ((l & 4) >> 1) | ((l & 8) >> 3);
    const bool b0 = l & 1, b1 = l & 2, b2 = l & 4, b3 = l & 8;

    h2t mrA[16], mrB[16];
#pragma unroll
    for (int i = 0; i < 16; ++i) {
      const float4 f =
          *reinterpret_cast<const float4*>(Mblk + (w * 16 + i) * 256 + 4 * l);
      mrA[i] = pack2(f.x, f.y);
      mrB[i] = pack2(f.z, f.w);
    }
    if (tid < 256) svs_f[tid] = 256.0f;
    __syncthreads();

    float sv256 = 1.0f;
    for (int it = 0; it < 8; ++it) {
      const float sv_tot =
          (it == 0) ? 257.0f : (wsumV[0] + wsumV[1] + wsumV[2] + wsumV[3] + sv256);
      const float su256 = 1.0f / (slack * sv_tot);
      // row pass
      const float4 va = *reinterpret_cast<const float4*>(&svs_f[4 * l]);
      const h2t sva = pack2(va.x, va.y), svb = pack2(va.z, va.w);
      float p[16];
#pragma unroll
      for (int i = 0; i < 16; ++i)
        p[i] = fdot2f(mrA[i], sva, fdot2f(mrB[i], svb, 0.0f));
#pragma unroll
      for (int i = 0; i < 8; ++i) {
        const float keep = b0 ? p[i + 8] : p[i], give = b0 ? p[i] : p[i + 8];
        p[i] = keep + dpp_get<0xB1>(give);
      }
#pragma unroll
      for (int i = 0; i < 4; ++i) {
        const float keep = b1 ? p[i + 4] : p[i], give = b1 ? p[i] : p[i + 4];
        p[i] = keep + dpp_get<0x4E>(give);
      }
#pragma unroll
      for (int i = 0; i < 2; ++i) {
        const float keep = b2 ? p[i + 2] : p[i], give = b2 ? p[i] : p[i + 2];
        p[i] = keep + dpp_get<0x141>(give);
      }
      {
        const float keep = b3 ? p[1] : p[0], give = b3 ? p[0] : p[1];
        p[0] = keep + dpp_get<0x140>(give);
      }
      float S = p[0];
      S += swz_get<0x401F>(S);
      S += __shfl_xor(S, 32, 64);
      const float su_val = 1.0f / (S * INV256 + slack * sv256);
      if (l < 16) su_f[w * 16 + rev] = su_val;
      const float wsU = allred16(su_val);
      if (l == 0) wsumU[w] = wsU;
      asm volatile("s_waitcnt lgkmcnt(0)" ::: "memory");
      // col partials from row regs
      float su16[16];
#pragma unroll
      for (int k = 0; k < 16; k += 4) {
        const float4 t = *reinterpret_cast<const float4*>(&su_f[w * 16 + k]);
        su16[k] = t.x; su16[k + 1] = t.y; su16[k + 2] = t.z; su16[k + 3] = t.w;
      }
      float pc0 = 0.f, pc1 = 0.f, pc2 = 0.f, pc3 = 0.f;
#pragma unroll
      for (int i = 0; i < 16; ++i) {
        const float ui = su16[i];
        pc0 = fmaf((float)mrA[i].x, ui, pc0);
        pc1 = fmaf((float)mrA[i].y, ui, pc1);
        pc2 = fmaf((float)mrB[i].x, ui, pc2);
        pc3 = fmaf((float)mrB[i].y, ui, pc3);
      }
      float4 pcv; pcv.x = pc0; pcv.y = pc1; pcv.z = pc2; pcv.w = pc3;
      *reinterpret_cast<float4*>(&psum[w][4 * l]) = pcv;
      __syncthreads();
      // sv phase
      const float su_tot = wsumU[0] + wsumU[1] + wsumU[2] + wsumU[3] + wsumU[4] +
                           wsumU[5] + wsumU[6] + wsumU[7] + wsumU[8] + wsumU[9] +
                           wsumU[10] + wsumU[11] + wsumU[12] + wsumU[13] +
                           wsumU[14] + wsumU[15] + su256;
      if (tid < 256) {
        float cs = 0.f;
#pragma unroll
        for (int g = 0; g < 16; ++g) cs += psum[g][tid];
        const float sv_val = 1.0f / (cs + slack * su256);
        svs_f[tid] = 256.0f * sv_val;
        float t = allred16(sv_val);
        t += swz_get<0x401F>(t);
        t += __shfl_xor(t, 32, 64);
        if (l == 0) wsumV[w] = t;
      }
      sv256 = 1.0f / (slack * su_tot);
      __syncthreads();
    }
    const float4 sv4 = *reinterpret_cast<const float4*>(&svs_f[4 * l]);
#pragma unroll
    for (int i = 0; i < 16; ++i) {
      const float uo = su_f[w * 16 + i] * INV256;
      float4 o;
      o.x = uo * (float)mrA[i].x * sv4.x;
      o.y = uo * (float)mrA[i].y * sv4.y;
      o.z = uo * (float)mrB[i].x * sv4.z;
      o.w = uo * (float)mrB[i].y * sv4.w;
      *reinterpret_cast<float4*>(outp + (w * 16 + i) * 256 + 4 * l) = o;
    }
  }
}

// ---------------------------------------------------------------------------
extern "C" void kernel_launch(void* const* d_in, const int* in_sizes, int n_in,
                              void* d_out, int out_size, void* d_ws, size_t ws_size,
                              hipStream_t stream) {
  (void)in_sizes; (void)n_in; (void)out_size; (void)ws_size;
  const float* x      = (const float*)d_in[0];
  const float* coords = (const float*)d_in[1];
  const float* co     = (const float*)d_in[2];
  // d_in[3] = edge_index (int32) — structure is deterministic, not needed
  const float* Wc    = (const float*)d_in[4];
  const float* bc    = (const float*)d_in[5];
  const float* Wapp1 = (const float*)d_in[6];
  const float* bapp1 = (const float*)d_in[7];
  const float* Wapp2 = (const float*)d_in[8];
  const float* bapp2 = (const float*)d_in[9];
  const float* Wg1   = (const float*)d_in[10];
  const float* bg1   = (const float*)d_in[11];
  const float* Wg2   = (const float*)d_in[12];
  const float* bg2   = (const float*)d_in[13];
  const float* Wa1   = (const float*)d_in[14];
  const float* ba1   = (const float*)d_in[15];
  const float* Wa2   = (const float*)d_in[16];
  const float* ba2   = (const float*)d_in[17];
  const float* Wo1   = (const float*)d_in[18];
  const float* Wo2   = (const float*)d_in[19];
  const float* bo    = (const float*)d_in[20];
  const float* Wf1   = (const float*)d_in[21];
  const float* bf1   = (const float*)d_in[22];
  const float* Wf2   = (const float*)d_in[23];
  const float* bf2   = (const float*)d_in[24];

  float* ws   = (float*)d_ws;
  float* h    = ws + 0;        // 512*256
  float* PQG  = ws + 131072;   // 512*512
  float* E1   = ws + 393216;   // 256*256
  float* E2   = ws + 458752;   // 256*256
  float* iou1 = ws + 524288;   // 256*256
  float* outm = ws + 589824;   // 512*256
  float* Mblk = ws + 720896;   // 256*256
  unsigned* flags = (unsigned*)(ws + 786432);  // [0..15] h rows, [16] edges, [17] score

  hipMemsetAsync(flags, 0, 128, stream);
  mega1<<<384, 256, 0, stream>>>(x, Wc, bc, h, Wapp1, bapp1, Wo2, PQG, flags);
  mega2<<<384, 256, 0, stream>>>(PQG, coords, co, Wapp2, bapp2, Wg1, bg1, Wg2,
                                 bg2, Wa1, ba1, Wa2, ba2, E1, E2, iou1, h, Wo1,
                                 bo, outm, flags + 16);
  mega3<<<65, 1024, 0, stream>>>(outm, iou1, Wf1, bf1, Wf2, bf2, Mblk,
                                 (float*)d_out, flags + 17);
}

// Round 8
// 103.041 us; speedup vs baseline: 7.1879x; 7.1879x over previous
//
#include <hip/hip_runtime.h>
#include <math.h>

// completeNet: graph-net + Sinkhorn, 6 dispatches (flag-fusion reverted:
// cross-XCD spin-flags are eviction-paced, ~600us — round 7 lesson).
// T=256 tracks (nodes 0..255), M=256 dets (nodes 256..511), D_IN=512, D_EMB=256.
// PQGW = h @ [Wapp1_P | Wapp1_Q | Wo2 | Wo1]  (512x768, stride 768):
//   cols 0..127 P(+bapp1), 128..255 Q, 256..511 G=h@Wo2, 512..767 HW1=h@Wo1.

__device__ __forceinline__ float sigmoidf_(float x) { return 1.0f / (1.0f + expf(-x)); }

typedef _Float16 h2t __attribute__((ext_vector_type(2)));

__device__ __forceinline__ h2t pack2(float x, float y) {
  h2t r; r.x = (_Float16)x; r.y = (_Float16)y; return r;
}
__device__ __forceinline__ float fdot2f(h2t a, h2t b, float c) {
  return __builtin_amdgcn_fdot2(a, b, c, false);
}
template <int CTRL>
__device__ __forceinline__ float dpp_get(float x) {
  return __builtin_bit_cast(
      float, __builtin_amdgcn_mov_dpp(__builtin_bit_cast(int, x), CTRL, 0xF, 0xF, false));
}
template <int IMM>
__device__ __forceinline__ float swz_get(float x) {
  return __builtin_bit_cast(
      float, __builtin_amdgcn_ds_swizzle(__builtin_bit_cast(int, x), IMM));
}
__device__ __forceinline__ float allred16(float x) {
  x += dpp_get<0xB1>(x);   // xor1
  x += dpp_get<0x4E>(x);   // xor2
  x += dpp_get<0x141>(x);  // xor7
  x += dpp_get<0x140>(x);  // xor15
  return x;
}

// ---------------------------------------------------------------------------
// K1: h = relu(x @ W_cnn + b_cnn)  (512x512)@(512x256), grid (8,16)
__global__ __launch_bounds__(256)
void k1_h(const float* __restrict__ x, const float* __restrict__ Wc,
          const float* __restrict__ bc, float* __restrict__ h) {
  __shared__ __align__(16) float Ast[2][32][36];
  const int tid = threadIdx.x;
  const int tx = tid & 31, ty = tid >> 5;
  const int ar = tid >> 3, ac = (tid & 7) * 4;
  const int bm = blockIdx.y * 32, bn = blockIdx.x * 32;
  const float* __restrict__ Bp = Wc + bn + tx;
  const float* __restrict__ Ap = x + (bm + ar) * 512 + ac;
  float4 aA, aB;
  float bA[32], bB[32];
  float acc[4] = {0.f, 0.f, 0.f, 0.f};

#define G_LOAD(T, AREG, BARR, AP, BP, LDB)                             \
  {                                                                    \
    AREG = *reinterpret_cast<const float4*>((AP) + (T) * 32);          \
    _Pragma("unroll") for (int kk = 0; kk < 32; ++kk)                  \
        BARR[kk] = (BP)[((T) * 32 + kk) * (LDB)];                      \
  }
#define G_STORE(BUF, AREG)                                             \
  {                                                                    \
    Ast[BUF][ac + 0][ar] = AREG.x; Ast[BUF][ac + 1][ar] = AREG.y;      \
    Ast[BUF][ac + 2][ar] = AREG.z; Ast[BUF][ac + 3][ar] = AREG.w;      \
  }
#define G_COMP(BUF, BARR)                                              \
  {                                                                    \
    _Pragma("unroll") for (int kk = 0; kk < 32; ++kk) {                \
      const float4 a4 =                                                \
          *reinterpret_cast<const float4*>(&Ast[BUF][kk][4 * ty]);     \
      const float bv = BARR[kk];                                       \
      acc[0] = fmaf(a4.x, bv, acc[0]); acc[1] = fmaf(a4.y, bv, acc[1]);\
      acc[2] = fmaf(a4.z, bv, acc[2]); acc[3] = fmaf(a4.w, bv, acc[3]);\
    }                                                                  \
  }

  G_LOAD(0, aA, bA, Ap, Bp, 256);
  G_STORE(0, aA);
  __syncthreads();
  for (int t = 0; t < 16; t += 2) {
    G_LOAD(t + 1, aB, bB, Ap, Bp, 256);
    G_COMP(0, bA);
    G_STORE(1, aB);
    __syncthreads();
    if (t + 2 < 16) { G_LOAD(t + 2, aA, bA, Ap, Bp, 256); }
    G_COMP(1, bB);
    if (t + 2 < 16) { G_STORE(0, aA); }
    __syncthreads();
  }
  const float bias = bc[bn + tx];
#pragma unroll
  for (int i = 0; i < 4; ++i) {
    const float vv = acc[i] + bias;
    h[(bm + 4 * ty + i) * 256 + bn + tx] = vv > 0.f ? vv : 0.f;
  }
}

// ---------------------------------------------------------------------------
// K2: PQGW (512x768), grid (24,16)
__global__ __launch_bounds__(256)
void k2_pqgw(const float* __restrict__ h, const float* __restrict__ W1,
             const float* __restrict__ b1, const float* __restrict__ Wo2,
             const float* __restrict__ Wo1, float* __restrict__ PQGW) {
  __shared__ __align__(16) float Ast[2][32][36];
  const int tid = threadIdx.x;
  const int tx = tid & 31, ty = tid >> 5;
  const int ar = tid >> 3, ac = (tid & 7) * 4;
  const int bm = blockIdx.y * 32, bn = blockIdx.x * 32;
  const int col = bn + tx;
  const float* __restrict__ Bp;
  int ldb;
  if (bn < 128)       { Bp = W1 + col; ldb = 128; }
  else if (bn < 256)  { Bp = W1 + 256 * 128 + (col - 128); ldb = 128; }
  else if (bn < 512)  { Bp = Wo2 + (col - 256); ldb = 256; }
  else                { Bp = Wo1 + (col - 512); ldb = 256; }
  const float* __restrict__ Ap = h + (bm + ar) * 256 + ac;
  float4 aA, aB;
  float bA[32], bB[32];
  float acc[4] = {0.f, 0.f, 0.f, 0.f};

  G_LOAD(0, aA, bA, Ap, Bp, ldb);
  G_STORE(0, aA);
  __syncthreads();
  for (int t = 0; t < 8; t += 2) {
    G_LOAD(t + 1, aB, bB, Ap, Bp, ldb);
    G_COMP(0, bA);
    G_STORE(1, aB);
    __syncthreads();
    if (t + 2 < 8) { G_LOAD(t + 2, aA, bA, Ap, Bp, ldb); }
    G_COMP(1, bB);
    if (t + 2 < 8) { G_STORE(0, aA); }
    __syncthreads();
  }
  const float bias = (bn < 128) ? b1[col] : 0.f;
#pragma unroll
  for (int i = 0; i < 4; ++i)
    PQGW[(bm + 4 * ty + i) * 768 + col] = acc[i] + bias;
}

// ---------------------------------------------------------------------------
// K3: edges, 256 blocks (block fr = track, BOTH directions), det P/Q rows
// chunk-staged through LDS (coalesced; validated in round 7's mega2).
__global__ __launch_bounds__(256)
void k3_edges(const float* __restrict__ PQGW, const float* __restrict__ coords,
              const float* __restrict__ co, const float* __restrict__ Wapp2,
              const float* __restrict__ bapp2, const float* __restrict__ Wg1,
              const float* __restrict__ bg1, const float* __restrict__ Wg2,
              const float* __restrict__ bg2, const float* __restrict__ Wa1,
              const float* __restrict__ ba1, const float* __restrict__ Wa2,
              const float* __restrict__ ba2, float* __restrict__ E1,
              float* __restrict__ E2, float* __restrict__ iou1) {
  __shared__ __align__(16) float Qs[256][33];
  __shared__ __align__(16) float sP[128], sQ[128], sW2[128];
  __shared__ __align__(16) float sWg1[256], sWg2[32], sGfix0[32], sGfix1[32];
  __shared__ float sWa1[16], sBa1[8], sWa2[8];
  const int tid = threadIdx.x;
  const int fr = blockIdx.x;
  if (tid < 128) {
    sP[tid] = PQGW[fr * 768 + tid];
    sQ[tid] = PQGW[fr * 768 + 128 + tid];
    sW2[tid] = Wapp2[tid];
  }
  sWg1[tid] = Wg1[tid];
  if (tid < 32) sWg2[tid] = Wg2[tid];
  if (tid < 16) sWa1[tid] = Wa1[tid];
  if (tid < 8) { sBa1[tid] = ba1[tid]; sWa2[tid] = Wa2[tid]; }
  __syncthreads();
  if (tid < 32) {
    float g0 = bg1[tid], g1 = g0;
#pragma unroll
    for (int q = 0; q < 4; ++q) {
      const float c = coords[fr * 4 + q];
      g0 = fmaf(c, sWg1[q * 32 + tid], g0);        // fr as src (E1)
      g1 = fmaf(c, sWg1[(4 + q) * 32 + tid], g1);  // fr as dst (E2)
    }
    sGfix0[tid] = g0;
    sGfix1[tid] = g1;
  }
  __syncthreads();

  const int d = tid;
  const int srow = tid >> 3, scq = (tid & 7) * 4;
  float z0 = 0.f, z1 = 0.f;
  for (int c8 = 0; c8 < 8; ++c8) {
    const int j0 = c8 * 32;
#pragma unroll
    for (int k = 0; k < 8; ++k) {
      const int r = k * 32 + srow;
      const float4 v = *reinterpret_cast<const float4*>(
          &PQGW[(256 + r) * 768 + j0 + scq]);
      Qs[r][scq + 0] = v.x; Qs[r][scq + 1] = v.y;
      Qs[r][scq + 2] = v.z; Qs[r][scq + 3] = v.w;
    }
    __syncthreads();
    if (j0 < 128) {  // P[det] cols -> pair with Q[fr] -> E2 (fr as dst)
#pragma unroll
      for (int j = 0; j < 32; ++j) {
        const int jj = j0 + j;
        float a = sQ[jj] + Qs[d][j];
        a = a > 0.f ? a : 0.f;
        z1 = fmaf(a, sW2[jj], z1);
      }
    } else {         // Q[det] cols -> pair with P[fr] -> E1 (fr as src)
#pragma unroll
      for (int j = 0; j < 32; ++j) {
        const int jj = j0 + j - 128;
        float a = sP[jj] + Qs[d][j];
        a = a > 0.f ? a : 0.f;
        z0 = fmaf(a, sW2[jj], z0);
      }
    }
    __syncthreads();
  }
  const float app0 = sigmoidf_(z0 + bapp2[0]);
  const float app1 = sigmoidf_(z1 + bapp2[0]);
  const float4 cp = *reinterpret_cast<const float4*>(coords + (256 + d) * 4);
  float gz0 = 0.f, gz1 = 0.f;
#pragma unroll
  for (int m = 0; m < 32; ++m) {
    float h0 = sGfix0[m];  // det in dst slot
    h0 = fmaf(cp.x, sWg1[(4 + 0) * 32 + m], h0);
    h0 = fmaf(cp.y, sWg1[(4 + 1) * 32 + m], h0);
    h0 = fmaf(cp.z, sWg1[(4 + 2) * 32 + m], h0);
    h0 = fmaf(cp.w, sWg1[(4 + 3) * 32 + m], h0);
    h0 = h0 > 0.f ? h0 : 0.f;
    gz0 = fmaf(h0, sWg2[m], gz0);
    float h1 = sGfix1[m];  // det in src slot
    h1 = fmaf(cp.x, sWg1[0 * 32 + m], h1);
    h1 = fmaf(cp.y, sWg1[1 * 32 + m], h1);
    h1 = fmaf(cp.z, sWg1[2 * 32 + m], h1);
    h1 = fmaf(cp.w, sWg1[3 * 32 + m], h1);
    h1 = h1 > 0.f ? h1 : 0.f;
    gz1 = fmaf(h1, sWg2[m], gz1);
  }
  const float geo0 = sigmoidf_(gz0 + bg2[0]);
  const float geo1 = sigmoidf_(gz1 + bg2[0]);
  float ez0 = 0.f, ez1 = 0.f;
#pragma unroll
  for (int m = 0; m < 8; ++m) {
    float h0 = fmaf(app0, sWa1[m], fmaf(geo0, sWa1[8 + m], sBa1[m]));
    h0 = h0 > 0.f ? h0 : 0.f;
    ez0 = fmaf(h0, sWa2[m], ez0);
    float h1 = fmaf(app1, sWa1[m], fmaf(geo1, sWa1[8 + m], sBa1[m]));
    h1 = h1 > 0.f ? h1 : 0.f;
    ez1 = fmaf(h1, sWa2[m], ez1);
  }
  E1[fr * 256 + d] = sigmoidf_(ez0 + ba2[0]);
  E2[fr * 256 + d] = sigmoidf_(ez1 + ba2[0]);
  const float4 A4 = *reinterpret_cast<const float4*>(co + fr * 4);
  const float4 B4 = *reinterpret_cast<const float4*>(co + (256 + d) * 4);
  const float ix1 = fmaxf(A4.x, B4.x), iy1 = fmaxf(A4.y, B4.y);
  const float ix2 = fminf(A4.z, B4.z), iy2 = fminf(A4.w, B4.w);
  const float inter = fmaxf(ix2 - ix1, 0.f) * fmaxf(iy2 - iy1, 0.f);
  const float areaA = (A4.z - A4.x) * (A4.w - A4.y);
  const float areaB = (B4.z - B4.x) * (B4.w - B4.y);
  iou1[fr * 256 + d] = inter / (areaA + areaB - inter + 1e-8f);
}

// ---------------------------------------------------------------------------
// K5: out = relu(HW1 + E@G + bo), K=256 only. grid (8,16).
__global__ __launch_bounds__(256)
void k5_out(const float* __restrict__ E1, const float* __restrict__ E2,
            const float* __restrict__ PQGW, const float* __restrict__ bo,
            float* __restrict__ outm) {
  __shared__ __align__(16) float Ast[2][32][36];
  const int tid = threadIdx.x;
  const int tx = tid & 31, ty = tid >> 5;
  const int ar = tid >> 3, ac = (tid & 7) * 4;
  const int bm = blockIdx.y * 32, bn = blockIdx.x * 32;
  const int col = bn + tx;
  const bool detrows = (bm >= 256);
  const float* __restrict__ Ap = detrows
      ? (E1 + ar * 256 + (bm - 256) + ac)   // direct: Ast[k][m]
      : (E2 + (bm + ar) * 256 + ac);        // transposed store
  const int astride = detrows ? 256 : 1;
  const float* __restrict__ Bp = PQGW + (detrows ? 0 : 256 * 768) + 256 + col;
  float4 aA, aB;
  float bA[32], bB[32];
  float acc[4] = {0.f, 0.f, 0.f, 0.f};

#define K5_LOAD(T, AREG, BARR)                                         \
  {                                                                    \
    AREG = *reinterpret_cast<const float4*>(Ap + (T) * 32 * astride);  \
    _Pragma("unroll") for (int kk = 0; kk < 32; ++kk)                  \
        BARR[kk] = Bp[((T) * 32 + kk) * 768];                          \
  }
#define K5_STORE(BUF, AREG)                                            \
  {                                                                    \
    if (detrows) {                                                     \
      *reinterpret_cast<float4*>(&Ast[BUF][ar][ac]) = AREG;            \
    } else {                                                           \
      Ast[BUF][ac + 0][ar] = AREG.x; Ast[BUF][ac + 1][ar] = AREG.y;    \
      Ast[BUF][ac + 2][ar] = AREG.z; Ast[BUF][ac + 3][ar] = AREG.w;    \
    }                                                                  \
  }

  K5_LOAD(0, aA, bA);
  K5_STORE(0, aA);
  __syncthreads();
  for (int t = 0; t < 8; t += 2) {
    K5_LOAD(t + 1, aB, bB);
    G_COMP(0, bA);
    K5_STORE(1, aB);
    __syncthreads();
    if (t + 2 < 8) { K5_LOAD(t + 2, aA, bA); }
    G_COMP(1, bB);
    if (t + 2 < 8) { K5_STORE(0, aA); }
    __syncthreads();
  }
  const float bias = bo[col];
#pragma unroll
  for (int i = 0; i < 4; ++i) {
    const float vv = acc[i] + bias + PQGW[(bm + 4 * ty + i) * 768 + 512 + col];
    outm[(bm + 4 * ty + i) * 256 + col] = vv > 0.f ? vv : 0.f;
  }
#undef K5_LOAD
#undef K5_STORE
}

// ---------------------------------------------------------------------------
// K6: score, 64 blocks x 1024 (4 track rows/block, det rows chunk-staged,
// shared by the 4 teams; validated in round 7's mega3).
__global__ __launch_bounds__(1024)
void k6_score(const float* __restrict__ outm, const float* __restrict__ iou1,
              const float* __restrict__ Wf1, const float* __restrict__ bf1,
              const float* __restrict__ Wf2, const float* __restrict__ bf2,
              float* __restrict__ Mblk) {
  __shared__ __align__(16) float so[4][260];
  __shared__ __align__(16) float ods[256][33];
  const int tid = threadIdx.x;
  const int team = tid >> 8, d = tid & 255;
  const int s = blockIdx.x * 4 + team;
  so[team][d] = outm[blockIdx.x * 1024 + tid];  // coalesced
  __syncthreads();
  float dot = 0.f, na2 = 0.f, nb2 = 0.f;
  for (int c8 = 0; c8 < 8; ++c8) {
    const int j0 = c8 * 32;
#pragma unroll
    for (int k = 0; k < 2; ++k) {
      const int qi = k * 1024 + tid;
      const int r = qi >> 3, cq = 4 * (qi & 7);
      const float4 v = *reinterpret_cast<const float4*>(
          &outm[(256 + r) * 256 + j0 + cq]);
      ods[r][cq + 0] = v.x; ods[r][cq + 1] = v.y;
      ods[r][cq + 2] = v.z; ods[r][cq + 3] = v.w;
    }
    __syncthreads();
#pragma unroll
    for (int j = 0; j < 32; ++j) {
      const float ov = ods[d][j];
      const float sv = so[team][j0 + j];
      dot = fmaf(sv, ov, dot);
      na2 = fmaf(sv, sv, na2);
      nb2 = fmaf(ov, ov, nb2);
    }
    __syncthreads();
  }
  const float na = fmaxf(sqrtf(na2), 1e-6f);
  const float nb = fmaxf(sqrtf(nb2), 1e-6f);
  const float cosv = dot / (na * nb);
  const float i1 = iou1[s * 256 + d];
  float sz = 0.f;
#pragma unroll
  for (int m = 0; m < 8; ++m) {
    float hm = fmaf(cosv, Wf1[m], fmaf(i1, Wf1[8 + m], bf1[m]));
    hm = hm > 0.f ? hm : 0.f;
    sz = fmaf(hm, Wf2[m], sz);
  }
  const float score = sigmoidf_(sz + bf2[0]);
  Mblk[s * 256 + d] = expf(5.0f * score);
}

// ---------------------------------------------------------------------------
// K7: Sinkhorn, single 1024-thread block, M register-resident (row fp16).
__global__ __launch_bounds__(1024)
void k7_sink(const float* __restrict__ Mg, float* __restrict__ outp) {
  __shared__ __align__(16) float su_f[256];
  __shared__ __align__(16) float svs_f[256];   // 256*sv
  __shared__ __align__(16) float psum[16][260];
  __shared__ float wsumU[16], wsumV[4];
  const int tid = threadIdx.x, w = tid >> 6, l = tid & 63;
  const float slack = 2.71828182845904523536f;  // exp(LAM*SLACK) = exp(1)
  const float INV256 = 0.00390625f;
  const int rev = ((l & 1) << 3) | ((l & 2) << 1) | ((l & 4) >> 1) | ((l & 8) >> 3);
  const bool b0 = l & 1, b1 = l & 2, b2 = l & 4, b3 = l & 8;

  h2t mrA[16], mrB[16];
#pragma unroll
  for (int i = 0; i < 16; ++i) {
    const float4 f = *reinterpret_cast<const float4*>(Mg + (w * 16 + i) * 256 + 4 * l);
    mrA[i] = pack2(f.x, f.y);
    mrB[i] = pack2(f.z, f.w);
  }
  if (tid < 256) svs_f[tid] = 256.0f;
  __syncthreads();

  float sv256 = 1.0f;
  for (int it = 0; it < 8; ++it) {
    const float sv_tot =
        (it == 0) ? 257.0f : (wsumV[0] + wsumV[1] + wsumV[2] + wsumV[3] + sv256);
    const float su256 = 1.0f / (slack * sv_tot);
    // row pass
    const float4 va = *reinterpret_cast<const float4*>(&svs_f[4 * l]);
    const h2t sva = pack2(va.x, va.y), svb = pack2(va.z, va.w);
    float p[16];
#pragma unroll
    for (int i = 0; i < 16; ++i) p[i] = fdot2f(mrA[i], sva, fdot2f(mrB[i], svb, 0.0f));
#pragma unroll
    for (int i = 0; i < 8; ++i) {
      const float keep = b0 ? p[i + 8] : p[i], give = b0 ? p[i] : p[i + 8];
      p[i] = keep + dpp_get<0xB1>(give);
    }
#pragma unroll
    for (int i = 0; i < 4; ++i) {
      const float keep = b1 ? p[i + 4] : p[i], give = b1 ? p[i] : p[i + 4];
      p[i] = keep + dpp_get<0x4E>(give);
    }
#pragma unroll
    for (int i = 0; i < 2; ++i) {
      const float keep = b2 ? p[i + 2] : p[i], give = b2 ? p[i] : p[i + 2];
      p[i] = keep + dpp_get<0x141>(give);
    }
    {
      const float keep = b3 ? p[1] : p[0], give = b3 ? p[0] : p[1];
      p[0] = keep + dpp_get<0x140>(give);
    }
    float S = p[0];
    S += swz_get<0x401F>(S);
    S += __shfl_xor(S, 32, 64);
    const float su_val = 1.0f / (S * INV256 + slack * sv256);
    if (l < 16) su_f[w * 16 + rev] = su_val;
    const float wsU = allred16(su_val);
    if (l == 0) wsumU[w] = wsU;
    asm volatile("s_waitcnt lgkmcnt(0)" ::: "memory");  // same-wave su_f readback
    // col partials from row regs
    float su16[16];
#pragma unroll
    for (int k = 0; k < 16; k += 4) {
      const float4 t = *reinterpret_cast<const float4*>(&su_f[w * 16 + k]);
      su16[k] = t.x; su16[k + 1] = t.y; su16[k + 2] = t.z; su16[k + 3] = t.w;
    }
    float pc0 = 0.f, pc1 = 0.f, pc2 = 0.f, pc3 = 0.f;
#pragma unroll
    for (int i = 0; i < 16; ++i) {
      const float ui = su16[i];
      pc0 = fmaf((float)mrA[i].x, ui, pc0);
      pc1 = fmaf((float)mrA[i].y, ui, pc1);
      pc2 = fmaf((float)mrB[i].x, ui, pc2);
      pc3 = fmaf((float)mrB[i].y, ui, pc3);
    }
    float4 pcv; pcv.x = pc0; pcv.y = pc1; pcv.z = pc2; pcv.w = pc3;
    *reinterpret_cast<float4*>(&psum[w][4 * l]) = pcv;
    __syncthreads();
    // sv phase
    const float su_tot = wsumU[0] + wsumU[1] + wsumU[2] + wsumU[3] + wsumU[4] +
                         wsumU[5] + wsumU[6] + wsumU[7] + wsumU[8] + wsumU[9] +
                         wsumU[10] + wsumU[11] + wsumU[12] + wsumU[13] +
                         wsumU[14] + wsumU[15] + su256;
    if (tid < 256) {
      float cs = 0.f;
#pragma unroll
      for (int g = 0; g < 16; ++g) cs += psum[g][tid];
      const float sv_val = 1.0f / (cs + slack * su256);
      svs_f[tid] = 256.0f * sv_val;
      float t = allred16(sv_val);
      t += swz_get<0x401F>(t);
      t += __shfl_xor(t, 32, 64);
      if (l == 0) wsumV[w] = t;
    }
    sv256 = 1.0f / (slack * su_tot);
    __syncthreads();
  }
  const float4 sv4 = *reinterpret_cast<const float4*>(&svs_f[4 * l]);
#pragma unroll
  for (int i = 0; i < 16; ++i) {
    const float uo = su_f[w * 16 + i] * INV256;
    float4 o;
    o.x = uo * (float)mrA[i].x * sv4.x;
    o.y = uo * (float)mrA[i].y * sv4.y;
    o.z = uo * (float)mrB[i].x * sv4.z;
    o.w = uo * (float)mrB[i].y * sv4.w;
    *reinterpret_cast<float4*>(outp + (w * 16 + i) * 256 + 4 * l) = o;
  }
}

// ---------------------------------------------------------------------------
extern "C" void kernel_launch(void* const* d_in, const int* in_sizes, int n_in,
                              void* d_out, int out_size, void* d_ws, size_t ws_size,
                              hipStream_t stream) {
  (void)in_sizes; (void)n_in; (void)out_size; (void)ws_size;
  const float* x      = (const float*)d_in[0];
  const float* coords = (const float*)d_in[1];
  const float* co     = (const float*)d_in[2];
  // d_in[3] = edge_index (int32) — structure is deterministic, not needed
  const float* Wc    = (const float*)d_in[4];
  const float* bc    = (const float*)d_in[5];
  const float* Wapp1 = (const float*)d_in[6];
  const float* bapp1 = (const float*)d_in[7];
  const float* Wapp2 = (const float*)d_in[8];
  const float* bapp2 = (const float*)d_in[9];
  const float* Wg1   = (const float*)d_in[10];
  const float* bg1   = (const float*)d_in[11];
  const float* Wg2   = (const float*)d_in[12];
  const float* bg2   = (const float*)d_in[13];
  const float* Wa1   = (const float*)d_in[14];
  const float* ba1   = (const float*)d_in[15];
  const float* Wa2   = (const float*)d_in[16];
  const float* ba2   = (const float*)d_in[17];
  const float* Wo1   = (const float*)d_in[18];
  const float* Wo2   = (const float*)d_in[19];
  const float* bo    = (const float*)d_in[20];
  const float* Wf1   = (const float*)d_in[21];
  const float* bf1   = (const float*)d_in[22];
  const float* Wf2   = (const float*)d_in[23];
  const float* bf2   = (const float*)d_in[24];

  float* ws   = (float*)d_ws;
  float* h    = ws + 0;        // 512*256
  float* PQGW = ws + 131072;   // 512*768
  float* E1   = ws + 524288;   // 256*256
  float* E2   = ws + 589824;   // 256*256
  float* iou1 = ws + 655360;   // 256*256
  float* outm = ws + 720896;   // 512*256
  float* Mblk = ws + 851968;   // 256*256

  k1_h<<<dim3(8, 16), 256, 0, stream>>>(x, Wc, bc, h);
  k2_pqgw<<<dim3(24, 16), 256, 0, stream>>>(h, Wapp1, bapp1, Wo2, Wo1, PQGW);
  k3_edges<<<256, 256, 0, stream>>>(PQGW, coords, co, Wapp2, bapp2, Wg1, bg1,
                                    Wg2, bg2, Wa1, ba1, Wa2, ba2, E1, E2, iou1);
  k5_out<<<dim3(8, 16), 256, 0, stream>>>(E1, E2, PQGW, bo, outm);
  k6_score<<<64, 1024, 0, stream>>>(outm, iou1, Wf1, bf1, Wf2, bf2, Mblk);
  k7_sink<<<1, 1024, 0, stream>>>(Mblk, (float*)d_out);
}

// Round 9
// 95.947 us; speedup vs baseline: 7.7193x; 1.0739x over previous
//
#include <hip/hip_runtime.h>
#include <math.h>

// completeNet: graph-net + Sinkhorn, 5 dispatches.
// T=256 tracks (nodes 0..255), M=256 dets (nodes 256..511), D_IN=512, D_EMB=256.
// PQGW = h @ [Wapp1_P | Wapp1_Q | Wo2 | Wo1] (512x768):
//   cols 0..127 P(+bapp1), 128..255 Q, 256..511 G=h@Wo2, 512..767 HW1=h@Wo1.
// k34: block b owns output row b. It computes the E-row it needs in-block
// (E[b,j] = e(src=varied j, dst=fixed b); unified path for track/det rows),
// then out[b] = relu(HW1[b] + sum_j E[b,j]*G[varied j] + bo) + row norm.
// E1/E2 never materialize. k6 = 64-block pipelined GEMM Out_track@Out_det^T
// with score-MLP epilogue.

__device__ __forceinline__ float sigmoidf_(float x) { return 1.0f / (1.0f + expf(-x)); }

typedef _Float16 h2t __attribute__((ext_vector_type(2)));

__device__ __forceinline__ h2t pack2(float x, float y) {
  h2t r; r.x = (_Float16)x; r.y = (_Float16)y; return r;
}
__device__ __forceinline__ float fdot2f(h2t a, h2t b, float c) {
  return __builtin_amdgcn_fdot2(a, b, c, false);
}
template <int CTRL>
__device__ __forceinline__ float dpp_get(float x) {
  return __builtin_bit_cast(
      float, __builtin_amdgcn_mov_dpp(__builtin_bit_cast(int, x), CTRL, 0xF, 0xF, false));
}
template <int IMM>
__device__ __forceinline__ float swz_get(float x) {
  return __builtin_bit_cast(
      float, __builtin_amdgcn_ds_swizzle(__builtin_bit_cast(int, x), IMM));
}
__device__ __forceinline__ float allred16(float x) {
  x += dpp_get<0xB1>(x);   // xor1
  x += dpp_get<0x4E>(x);   // xor2
  x += dpp_get<0x141>(x);  // xor7
  x += dpp_get<0x140>(x);  // xor15
  return x;
}

#define G_LOAD(T, AREG, BARR, AP, BP, LDB)                             \
  {                                                                    \
    AREG = *reinterpret_cast<const float4*>((AP) + (T) * 32);          \
    _Pragma("unroll") for (int kk = 0; kk < 32; ++kk)                  \
        BARR[kk] = (BP)[((T) * 32 + kk) * (LDB)];                      \
  }
#define G_STORE(BUF, AREG)                                             \
  {                                                                    \
    Ast[BUF][ac + 0][ar] = AREG.x; Ast[BUF][ac + 1][ar] = AREG.y;      \
    Ast[BUF][ac + 2][ar] = AREG.z; Ast[BUF][ac + 3][ar] = AREG.w;      \
  }
#define G_COMP(BUF, BARR)                                              \
  {                                                                    \
    _Pragma("unroll") for (int kk = 0; kk < 32; ++kk) {                \
      const float4 a4 =                                                \
          *reinterpret_cast<const float4*>(&Ast[BUF][kk][4 * ty]);     \
      const float bv = BARR[kk];                                       \
      acc[0] = fmaf(a4.x, bv, acc[0]); acc[1] = fmaf(a4.y, bv, acc[1]);\
      acc[2] = fmaf(a4.z, bv, acc[2]); acc[3] = fmaf(a4.w, bv, acc[3]);\
    }                                                                  \
  }

// ---------------------------------------------------------------------------
// K1: h = relu(x @ W_cnn + b_cnn)  (512x512)@(512x256), grid (8,16)
__global__ __launch_bounds__(256)
void k1_h(const float* __restrict__ x, const float* __restrict__ Wc,
          const float* __restrict__ bc, float* __restrict__ h) {
  __shared__ __align__(16) float Ast[2][32][36];
  const int tid = threadIdx.x;
  const int tx = tid & 31, ty = tid >> 5;
  const int ar = tid >> 3, ac = (tid & 7) * 4;
  const int bm = blockIdx.y * 32, bn = blockIdx.x * 32;
  const float* __restrict__ Bp = Wc + bn + tx;
  const float* __restrict__ Ap = x + (bm + ar) * 512 + ac;
  float4 aA, aB;
  float bA[32], bB[32];
  float acc[4] = {0.f, 0.f, 0.f, 0.f};

  G_LOAD(0, aA, bA, Ap, Bp, 256);
  G_STORE(0, aA);
  __syncthreads();
  for (int t = 0; t < 16; t += 2) {
    G_LOAD(t + 1, aB, bB, Ap, Bp, 256);
    G_COMP(0, bA);
    G_STORE(1, aB);
    __syncthreads();
    if (t + 2 < 16) { G_LOAD(t + 2, aA, bA, Ap, Bp, 256); }
    G_COMP(1, bB);
    if (t + 2 < 16) { G_STORE(0, aA); }
    __syncthreads();
  }
  const float bias = bc[bn + tx];
#pragma unroll
  for (int i = 0; i < 4; ++i) {
    const float vv = acc[i] + bias;
    h[(bm + 4 * ty + i) * 256 + bn + tx] = vv > 0.f ? vv : 0.f;
  }
}

// ---------------------------------------------------------------------------
// K2: PQGW (512x768), grid (24,16)
__global__ __launch_bounds__(256)
void k2_pqgw(const float* __restrict__ h, const float* __restrict__ W1,
             const float* __restrict__ b1, const float* __restrict__ Wo2,
             const float* __restrict__ Wo1, float* __restrict__ PQGW) {
  __shared__ __align__(16) float Ast[2][32][36];
  const int tid = threadIdx.x;
  const int tx = tid & 31, ty = tid >> 5;
  const int ar = tid >> 3, ac = (tid & 7) * 4;
  const int bm = blockIdx.y * 32, bn = blockIdx.x * 32;
  const int col = bn + tx;
  const float* __restrict__ Bp;
  int ldb;
  if (bn < 128)       { Bp = W1 + col; ldb = 128; }
  else if (bn < 256)  { Bp = W1 + 256 * 128 + (col - 128); ldb = 128; }
  else if (bn < 512)  { Bp = Wo2 + (col - 256); ldb = 256; }
  else                { Bp = Wo1 + (col - 512); ldb = 256; }
  const float* __restrict__ Ap = h + (bm + ar) * 256 + ac;
  float4 aA, aB;
  float bA[32], bB[32];
  float acc[4] = {0.f, 0.f, 0.f, 0.f};

  G_LOAD(0, aA, bA, Ap, Bp, ldb);
  G_STORE(0, aA);
  __syncthreads();
  for (int t = 0; t < 8; t += 2) {
    G_LOAD(t + 1, aB, bB, Ap, Bp, ldb);
    G_COMP(0, bA);
    G_STORE(1, aB);
    __syncthreads();
    if (t + 2 < 8) { G_LOAD(t + 2, aA, bA, Ap, Bp, ldb); }
    G_COMP(1, bB);
    if (t + 2 < 8) { G_STORE(0, aA); }
    __syncthreads();
  }
  const float bias = (bn < 128) ? b1[col] : 0.f;
#pragma unroll
  for (int i = 0; i < 4; ++i)
    PQGW[(bm + 4 * ty + i) * 768 + col] = acc[i] + bias;
}

// ---------------------------------------------------------------------------
// K34: 512 blocks; block b owns output row b (b<256: track, else det).
// Edge row -> sE (LDS), then out row + row norm. iou row only for b<256.
__global__ __launch_bounds__(256)
void k34_edges_out(const float* __restrict__ PQGW, const float* __restrict__ coords,
                   const float* __restrict__ co, const float* __restrict__ Wapp2,
                   const float* __restrict__ bapp2, const float* __restrict__ Wg1,
                   const float* __restrict__ bg1, const float* __restrict__ Wg2,
                   const float* __restrict__ bg2, const float* __restrict__ Wa1,
                   const float* __restrict__ ba1, const float* __restrict__ Wa2,
                   const float* __restrict__ ba2, const float* __restrict__ bo,
                   float* __restrict__ iou1, float* __restrict__ outm,
                   float* __restrict__ nrm) {
  __shared__ __align__(16) float sQ[128], sW2[128], sWg1[256], sWg2[32], sGfix[32];
  __shared__ __align__(16) float sE[256];
  __shared__ float sWa1[16], sBa1[8], sWa2[8], wpart[4];
  const int tid = threadIdx.x;
  const int b = blockIdx.x;
  const bool istrack = (b < 256);
  const int vbase = istrack ? 256 : 0;   // varied node base (src side)

  if (tid < 128) {
    sQ[tid] = PQGW[b * 768 + 128 + tid];  // Q[fixed b] (dst side)
    sW2[tid] = Wapp2[tid];
  }
  sWg1[tid] = Wg1[tid];
  if (tid < 32) sWg2[tid] = Wg2[tid];
  if (tid < 16) sWa1[tid] = Wa1[tid];
  if (tid < 8) { sBa1[tid] = ba1[tid]; sWa2[tid] = Wa2[tid]; }
  __syncthreads();
  if (tid < 32) {  // fixed node in DST slot: Wg1 rows 4..7
    float g = bg1[tid];
#pragma unroll
    for (int q = 0; q < 4; ++q)
      g = fmaf(coords[b * 4 + q], sWg1[(4 + q) * 32 + tid], g);
    sGfix[tid] = g;
  }
  __syncthreads();

  const int vr = vbase + tid;  // varied node (src side)
  // app: pre = P[varied] + Q[fixed]
  const float* prow = PQGW + vr * 768;
  float z = 0.f;
#pragma unroll
  for (int j = 0; j < 128; j += 4) {
    const float4 p4 = *reinterpret_cast<const float4*>(prow + j);
    const float4 q4 = *reinterpret_cast<const float4*>(&sQ[j]);
    const float4 w4 = *reinterpret_cast<const float4*>(&sW2[j]);
    float a;
    a = p4.x + q4.x; a = a > 0.f ? a : 0.f; z = fmaf(a, w4.x, z);
    a = p4.y + q4.y; a = a > 0.f ? a : 0.f; z = fmaf(a, w4.y, z);
    a = p4.z + q4.z; a = a > 0.f ? a : 0.f; z = fmaf(a, w4.z, z);
    a = p4.w + q4.w; a = a > 0.f ? a : 0.f; z = fmaf(a, w4.w, z);
  }
  const float app = sigmoidf_(z + bapp2[0]);
  // geo: varied node in SRC slot: Wg1 rows 0..3
  const float4 cp = *reinterpret_cast<const float4*>(coords + vr * 4);
  float gz = 0.f;
#pragma unroll
  for (int m = 0; m < 32; ++m) {
    float hm = sGfix[m];
    hm = fmaf(cp.x, sWg1[0 * 32 + m], hm);
    hm = fmaf(cp.y, sWg1[1 * 32 + m], hm);
    hm = fmaf(cp.z, sWg1[2 * 32 + m], hm);
    hm = fmaf(cp.w, sWg1[3 * 32 + m], hm);
    hm = hm > 0.f ? hm : 0.f;
    gz = fmaf(hm, sWg2[m], gz);
  }
  const float geo = sigmoidf_(gz + bg2[0]);
  float ez = 0.f;
#pragma unroll
  for (int m = 0; m < 8; ++m) {
    float hm = fmaf(app, sWa1[m], fmaf(geo, sWa1[8 + m], sBa1[m]));
    hm = hm > 0.f ? hm : 0.f;
    ez = fmaf(hm, sWa2[m], ez);
  }
  sE[tid] = sigmoidf_(ez + ba2[0]);
  if (istrack) {  // iou row (first-half edges (b, 256+tid))
    const float4 A4 = *reinterpret_cast<const float4*>(co + b * 4);
    const float4 B4 = *reinterpret_cast<const float4*>(co + (256 + tid) * 4);
    const float ix1 = fmaxf(A4.x, B4.x), iy1 = fmaxf(A4.y, B4.y);
    const float ix2 = fminf(A4.z, B4.z), iy2 = fminf(A4.w, B4.w);
    const float inter = fmaxf(ix2 - ix1, 0.f) * fmaxf(iy2 - iy1, 0.f);
    const float areaA = (A4.z - A4.x) * (A4.w - A4.y);
    const float areaB = (B4.z - B4.x) * (B4.w - B4.y);
    iou1[b * 256 + tid] = inter / (areaA + areaB - inter + 1e-8f);
  }
  __syncthreads();

  // out row: c = tid. acc = HW1[b][c] + sum_j sE[j] * G[vbase+j][c]
  const int c = tid;
  float a0 = 0.f, a1 = 0.f, a2 = 0.f, a3 = 0.f;
  const float* gcol = PQGW + vbase * 768 + 256 + c;
#pragma unroll 4
  for (int j = 0; j < 256; j += 4) {
    const float4 e4 = *reinterpret_cast<const float4*>(&sE[j]);
    a0 = fmaf(e4.x, gcol[(j + 0) * 768], a0);
    a1 = fmaf(e4.y, gcol[(j + 1) * 768], a1);
    a2 = fmaf(e4.z, gcol[(j + 2) * 768], a2);
    a3 = fmaf(e4.w, gcol[(j + 3) * 768], a3);
  }
  const float base = PQGW[b * 768 + 512 + c] + bo[c];
  float vv = base + ((a0 + a1) + (a2 + a3));
  vv = vv > 0.f ? vv : 0.f;
  outm[b * 256 + c] = vv;
  // row norm
  float nsq = vv * vv;
  nsq = allred16(nsq);
  nsq += swz_get<0x401F>(nsq);          // xor16
  nsq += __shfl_xor(nsq, 32, 64);       // xor32
  if ((tid & 63) == 0) wpart[tid >> 6] = nsq;
  __syncthreads();
  if (tid == 0)
    nrm[b] = fmaxf(sqrtf(wpart[0] + wpart[1] + wpart[2] + wpart[3]), 1e-6f);
}

// ---------------------------------------------------------------------------
// K6: Mblk = exp(5*score(cos, iou)). 64-block GEMM: Out_track @ Out_det^T,
// B streamed row-per-thread (ldb=1), score-MLP epilogue. grid (8,8).
__global__ __launch_bounds__(256)
void k6_score(const float* __restrict__ outm, const float* __restrict__ nrm,
              const float* __restrict__ iou1, const float* __restrict__ Wf1,
              const float* __restrict__ bf1, const float* __restrict__ Wf2,
              const float* __restrict__ bf2, float* __restrict__ Mblk) {
  __shared__ __align__(16) float Ast[2][32][36];
  const int tid = threadIdx.x;
  const int tx = tid & 31, ty = tid >> 5;
  const int ar = tid >> 3, ac = (tid & 7) * 4;
  const int s0 = blockIdx.y * 32, d0 = blockIdx.x * 32;
  const float* __restrict__ Ap = outm + (s0 + ar) * 256 + ac;
  const float* __restrict__ Bp = outm + (256 + d0 + tx) * 256;  // det row, ldb=1
  float4 aA, aB;
  float bA[32], bB[32];
  float acc[4] = {0.f, 0.f, 0.f, 0.f};

  G_LOAD(0, aA, bA, Ap, Bp, 1);
  G_STORE(0, aA);
  __syncthreads();
  for (int t = 0; t < 8; t += 2) {
    G_LOAD(t + 1, aB, bB, Ap, Bp, 1);
    G_COMP(0, bA);
    G_STORE(1, aB);
    __syncthreads();
    if (t + 2 < 8) { G_LOAD(t + 2, aA, bA, Ap, Bp, 1); }
    G_COMP(1, bB);
    if (t + 2 < 8) { G_STORE(0, aA); }
    __syncthreads();
  }
  const float nb = nrm[256 + d0 + tx];
  float w1c[8], w1i[8], w2[8];
#pragma unroll
  for (int m = 0; m < 8; ++m) {
    w1c[m] = Wf1[m]; w1i[m] = Wf1[8 + m]; w2[m] = Wf2[m];
  }
  const float bf20 = bf2[0];
#pragma unroll
  for (int i = 0; i < 4; ++i) {
    const int r = s0 + 4 * ty + i;
    const float cosv = acc[i] / (nrm[r] * nb);
    const float i1 = iou1[r * 256 + d0 + tx];
    float sz = 0.f;
#pragma unroll
    for (int m = 0; m < 8; ++m) {
      float hm = fmaf(cosv, w1c[m], fmaf(i1, w1i[m], bf1[m]));
      hm = hm > 0.f ? hm : 0.f;
      sz = fmaf(hm, w2[m], sz);
    }
    const float score = sigmoidf_(sz + bf20);
    Mblk[r * 256 + d0 + tx] = expf(5.0f * score);
  }
}

// ---------------------------------------------------------------------------
// K7: Sinkhorn, single 1024-thread block, M register-resident (row fp16).
__global__ __launch_bounds__(1024)
void k7_sink(const float* __restrict__ Mg, float* __restrict__ outp) {
  __shared__ __align__(16) float su_f[256];
  __shared__ __align__(16) float svs_f[256];   // 256*sv
  __shared__ __align__(16) float psum[16][260];
  __shared__ float wsumU[16], wsumV[4];
  const int tid = threadIdx.x, w = tid >> 6, l = tid & 63;
  const float slack = 2.71828182845904523536f;  // exp(LAM*SLACK) = exp(1)
  const float INV256 = 0.00390625f;
  const int rev = ((l & 1) << 3) | ((l & 2) << 1) | ((l & 4) >> 1) | ((l & 8) >> 3);
  const bool b0 = l & 1, b1 = l & 2, b2 = l & 4, b3 = l & 8;

  h2t mrA[16], mrB[16];
#pragma unroll
  for (int i = 0; i < 16; ++i) {
    const float4 f = *reinterpret_cast<const float4*>(Mg + (w * 16 + i) * 256 + 4 * l);
    mrA[i] = pack2(f.x, f.y);
    mrB[i] = pack2(f.z, f.w);
  }
  if (tid < 256) svs_f[tid] = 256.0f;
  __syncthreads();

  float sv256 = 1.0f;
  for (int it = 0; it < 8; ++it) {
    const float sv_tot =
        (it == 0) ? 257.0f : (wsumV[0] + wsumV[1] + wsumV[2] + wsumV[3] + sv256);
    const float su256 = 1.0f / (slack * sv_tot);
    // row pass
    const float4 va = *reinterpret_cast<const float4*>(&svs_f[4 * l]);
    const h2t sva = pack2(va.x, va.y), svb = pack2(va.z, va.w);
    float p[16];
#pragma unroll
    for (int i = 0; i < 16; ++i) p[i] = fdot2f(mrA[i], sva, fdot2f(mrB[i], svb, 0.0f));
#pragma unroll
    for (int i = 0; i < 8; ++i) {
      const float keep = b0 ? p[i + 8] : p[i], give = b0 ? p[i] : p[i + 8];
      p[i] = keep + dpp_get<0xB1>(give);
    }
#pragma unroll
    for (int i = 0; i < 4; ++i) {
      const float keep = b1 ? p[i + 4] : p[i], give = b1 ? p[i] : p[i + 4];
      p[i] = keep + dpp_get<0x4E>(give);
    }
#pragma unroll
    for (int i = 0; i < 2; ++i) {
      const float keep = b2 ? p[i + 2] : p[i], give = b2 ? p[i] : p[i + 2];
      p[i] = keep + dpp_get<0x141>(give);
    }
    {
      const float keep = b3 ? p[1] : p[0], give = b3 ? p[0] : p[1];
      p[0] = keep + dpp_get<0x140>(give);
    }
    float S = p[0];
    S += swz_get<0x401F>(S);
    S += __shfl_xor(S, 32, 64);
    const float su_val = 1.0f / (S * INV256 + slack * sv256);
    if (l < 16) su_f[w * 16 + rev] = su_val;
    const float wsU = allred16(su_val);
    if (l == 0) wsumU[w] = wsU;
    asm volatile("s_waitcnt lgkmcnt(0)" ::: "memory");  // same-wave su_f readback
    // col partials from row regs
    float su16[16];
#pragma unroll
    for (int k = 0; k < 16; k += 4) {
      const float4 t = *reinterpret_cast<const float4*>(&su_f[w * 16 + k]);
      su16[k] = t.x; su16[k + 1] = t.y; su16[k + 2] = t.z; su16[k + 3] = t.w;
    }
    float pc0 = 0.f, pc1 = 0.f, pc2 = 0.f, pc3 = 0.f;
#pragma unroll
    for (int i = 0; i < 16; ++i) {
      const float ui = su16[i];
      pc0 = fmaf((float)mrA[i].x, ui, pc0);
      pc1 = fmaf((float)mrA[i].y, ui, pc1);
      pc2 = fmaf((float)mrB[i].x, ui, pc2);
      pc3 = fmaf((float)mrB[i].y, ui, pc3);
    }
    float4 pcv; pcv.x = pc0; pcv.y = pc1; pcv.z = pc2; pcv.w = pc3;
    *reinterpret_cast<float4*>(&psum[w][4 * l]) = pcv;
    __syncthreads();
    // sv phase
    const float su_tot = wsumU[0] + wsumU[1] + wsumU[2] + wsumU[3] + wsumU[4] +
                         wsumU[5] + wsumU[6] + wsumU[7] + wsumU[8] + wsumU[9] +
                         wsumU[10] + wsumU[11] + wsumU[12] + wsumU[13] +
                         wsumU[14] + wsumU[15] + su256;
    if (tid < 256) {
      float cs = 0.f;
#pragma unroll
      for (int g = 0; g < 16; ++g) cs += psum[g][tid];
      const float sv_val = 1.0f / (cs + slack * su256);
      svs_f[tid] = 256.0f * sv_val;
      float t = allred16(sv_val);
      t += swz_get<0x401F>(t);
      t += __shfl_xor(t, 32, 64);
      if (l == 0) wsumV[w] = t;
    }
    sv256 = 1.0f / (slack * su_tot);
    __syncthreads();
  }
  const float4 sv4 = *reinterpret_cast<const float4*>(&svs_f[4 * l]);
#pragma unroll
  for (int i = 0; i < 16; ++i) {
    const float uo = su_f[w * 16 + i] * INV256;
    float4 o;
    o.x = uo * (float)mrA[i].x * sv4.x;
    o.y = uo * (float)mrA[i].y * sv4.y;
    o.z = uo * (float)mrB[i].x * sv4.z;
    o.w = uo * (float)mrB[i].y * sv4.w;
    *reinterpret_cast<float4*>(outp + (w * 16 + i) * 256 + 4 * l) = o;
  }
}

// ---------------------------------------------------------------------------
extern "C" void kernel_launch(void* const* d_in, const int* in_sizes, int n_in,
                              void* d_out, int out_size, void* d_ws, size_t ws_size,
                              hipStream_t stream) {
  (void)in_sizes; (void)n_in; (void)out_size; (void)ws_size;
  const float* x      = (const float*)d_in[0];
  const float* coords = (const float*)d_in[1];
  const float* co     = (const float*)d_in[2];
  // d_in[3] = edge_index (int32) — structure is deterministic, not needed
  const float* Wc    = (const float*)d_in[4];
  const float* bc    = (const float*)d_in[5];
  const float* Wapp1 = (const float*)d_in[6];
  const float* bapp1 = (const float*)d_in[7];
  const float* Wapp2 = (const float*)d_in[8];
  const float* bapp2 = (const float*)d_in[9];
  const float* Wg1   = (const float*)d_in[10];
  const float* bg1   = (const float*)d_in[11];
  const float* Wg2   = (const float*)d_in[12];
  const float* bg2   = (const float*)d_in[13];
  const float* Wa1   = (const float*)d_in[14];
  const float* ba1   = (const float*)d_in[15];
  const float* Wa2   = (const float*)d_in[16];
  const float* ba2   = (const float*)d_in[17];
  const float* Wo1   = (const float*)d_in[18];
  const float* Wo2   = (const float*)d_in[19];
  const float* bo    = (const float*)d_in[20];
  const float* Wf1   = (const float*)d_in[21];
  const float* bf1   = (const float*)d_in[22];
  const float* Wf2   = (const float*)d_in[23];
  const float* bf2   = (const float*)d_in[24];

  float* ws   = (float*)d_ws;
  float* h    = ws + 0;        // 512*256
  float* PQGW = ws + 131072;   // 512*768
  float* iou1 = ws + 524288;   // 256*256
  float* outm = ws + 589824;   // 512*256
  float* nrm  = ws + 720896;   // 512
  float* Mblk = ws + 721408;   // 256*256

  k1_h<<<dim3(8, 16), 256, 0, stream>>>(x, Wc, bc, h);
  k2_pqgw<<<dim3(24, 16), 256, 0, stream>>>(h, Wapp1, bapp1, Wo2, Wo1, PQGW);
  k34_edges_out<<<512, 256, 0, stream>>>(PQGW, coords, co, Wapp2, bapp2, Wg1,
                                         bg1, Wg2, bg2, Wa1, ba1, Wa2, ba2, bo,
                                         iou1, outm, nrm);
  k6_score<<<dim3(8, 8), 256, 0, stream>>>(outm, nrm, iou1, Wf1, bf1, Wf2, bf2,
                                           Mblk);
  k7_sink<<<1, 1024, 0, stream>>>(Mblk, (float*)d_out);
}

// Round 10
// 88.664 us; speedup vs baseline: 8.3534x; 1.0821x over previous
//
#include <hip/hip_runtime.h>
#include <math.h>

// completeNet: graph-net + Sinkhorn, 5 dispatches.
// T=256 tracks (nodes 0..255), M=256 dets (nodes 256..511), D_IN=512, D_EMB=256.
// Round-10 layout:
//   k1: hAB[2][512][256] = x@Wc K-halves (raw, no relu/bias), grid (8,16,2).
//   k2: A = relu(hA+hB+bc) fused in-load. Writes:
//       PT[128][512]  = P^T (+bapp1)  <- transposed so k34's app reads coalesce
//       PQGW[512][768] cols 128..255 Q, 256..511 G=h@Wo2, 512..767 HW1=h@Wo1
//       (cols 0..127 of PQGW unused/unwritten).
//   k34: block b owns output row b; computes its E-row in-block (E[b,j] =
//        e(src=j, dst=b)), out[b] = relu(HW1[b] + sum_j E[b,j]*G[j] + bo), norm.
//   k6: 64-block GEMM Out_track@Out_det^T + inline iou + score MLP -> Mblk.
//   k7: Sinkhorn, 1 block, M register-resident fp16.

__device__ __forceinline__ float sigmoidf_(float x) { return 1.0f / (1.0f + expf(-x)); }

typedef _Float16 h2t __attribute__((ext_vector_type(2)));

__device__ __forceinline__ h2t pack2(float x, float y) {
  h2t r; r.x = (_Float16)x; r.y = (_Float16)y; return r;
}
__device__ __forceinline__ float fdot2f(h2t a, h2t b, float c) {
  return __builtin_amdgcn_fdot2(a, b, c, false);
}
template <int CTRL>
__device__ __forceinline__ float dpp_get(float x) {
  return __builtin_bit_cast(
      float, __builtin_amdgcn_mov_dpp(__builtin_bit_cast(int, x), CTRL, 0xF, 0xF, false));
}
template <int IMM>
__device__ __forceinline__ float swz_get(float x) {
  return __builtin_bit_cast(
      float, __builtin_amdgcn_ds_swizzle(__builtin_bit_cast(int, x), IMM));
}
__device__ __forceinline__ float allred16(float x) {
  x += dpp_get<0xB1>(x);   // xor1
  x += dpp_get<0x4E>(x);   // xor2
  x += dpp_get<0x141>(x);  // xor7
  x += dpp_get<0x140>(x);  // xor15
  return x;
}

#define G_LOAD(T, AREG, BARR, AP, BP, LDB)                             \
  {                                                                    \
    AREG = *reinterpret_cast<const float4*>((AP) + (T) * 32);          \
    _Pragma("unroll") for (int kk = 0; kk < 32; ++kk)                  \
        BARR[kk] = (BP)[((T) * 32 + kk) * (LDB)];                      \
  }
#define G_STORE(BUF, AREG)                                             \
  {                                                                    \
    Ast[BUF][ac + 0][ar] = AREG.x; Ast[BUF][ac + 1][ar] = AREG.y;      \
    Ast[BUF][ac + 2][ar] = AREG.z; Ast[BUF][ac + 3][ar] = AREG.w;      \
  }
#define G_COMP(BUF, BARR)                                              \
  {                                                                    \
    _Pragma("unroll") for (int kk = 0; kk < 32; ++kk) {                \
      const float4 a4 =                                                \
          *reinterpret_cast<const float4*>(&Ast[BUF][kk][4 * ty]);     \
      const float bv = BARR[kk];                                       \
      acc[0] = fmaf(a4.x, bv, acc[0]); acc[1] = fmaf(a4.y, bv, acc[1]);\
      acc[2] = fmaf(a4.z, bv, acc[2]); acc[3] = fmaf(a4.w, bv, acc[3]);\
    }                                                                  \
  }

// ---------------------------------------------------------------------------
// K1: hAB[z] = x[:, z*256:(z+1)*256] @ Wc[z*256:(z+1)*256, :]  (raw partials)
// grid (8,16,2) = 256 blocks.
__global__ __launch_bounds__(256)
void k1_h(const float* __restrict__ x, const float* __restrict__ Wc,
          float* __restrict__ hAB) {
  __shared__ __align__(16) float Ast[2][32][36];
  const int tid = threadIdx.x;
  const int tx = tid & 31, ty = tid >> 5;
  const int ar = tid >> 3, ac = (tid & 7) * 4;
  const int bm = blockIdx.y * 32, bn = blockIdx.x * 32;
  const int z = blockIdx.z;
  const float* __restrict__ Bp = Wc + (z * 256) * 256 + bn + tx;
  const float* __restrict__ Ap = x + (bm + ar) * 512 + z * 256 + ac;
  float* __restrict__ Cout = hAB + z * 131072;
  float4 aA, aB;
  float bA[32], bB[32];
  float acc[4] = {0.f, 0.f, 0.f, 0.f};

  G_LOAD(0, aA, bA, Ap, Bp, 256);
  G_STORE(0, aA);
  __syncthreads();
  for (int t = 0; t < 8; t += 2) {
    G_LOAD(t + 1, aB, bB, Ap, Bp, 256);
    G_COMP(0, bA);
    G_STORE(1, aB);
    __syncthreads();
    if (t + 2 < 8) { G_LOAD(t + 2, aA, bA, Ap, Bp, 256); }
    G_COMP(1, bB);
    if (t + 2 < 8) { G_STORE(0, aA); }
    __syncthreads();
  }
#pragma unroll
  for (int i = 0; i < 4; ++i)
    Cout[(bm + 4 * ty + i) * 256 + bn + tx] = acc[i];
}

// ---------------------------------------------------------------------------
// K2: A = relu(hA+hB+bc) in-load. Out: PT (bn<128, transposed, +bapp1) or
// PQGW cols 128..767. grid (24,16) = 384 blocks.
__global__ __launch_bounds__(256)
void k2_pqgw(const float* __restrict__ hAB, const float* __restrict__ bc,
             const float* __restrict__ W1, const float* __restrict__ b1,
             const float* __restrict__ Wo2, const float* __restrict__ Wo1,
             float* __restrict__ PQGW, float* __restrict__ PT) {
  __shared__ __align__(16) float Ast[2][32][36];
  const int tid = threadIdx.x;
  const int tx = tid & 31, ty = tid >> 5;
  const int ar = tid >> 3, ac = (tid & 7) * 4;
  const int bm = blockIdx.y * 32, bn = blockIdx.x * 32;
  const int col = bn + tx;
  const float* __restrict__ Bp;
  int ldb;
  if (bn < 128)       { Bp = W1 + col; ldb = 128; }
  else if (bn < 256)  { Bp = W1 + 256 * 128 + (col - 128); ldb = 128; }
  else if (bn < 512)  { Bp = Wo2 + (col - 256); ldb = 256; }
  else                { Bp = Wo1 + (col - 512); ldb = 256; }
  const float* __restrict__ ApA = hAB + (bm + ar) * 256 + ac;
  const float* __restrict__ ApB = ApA + 131072;
  const float* __restrict__ bcp = bc + ac;
  float4 aA, aB;
  float bA[32], bB[32];
  float acc[4] = {0.f, 0.f, 0.f, 0.f};

#define K2_LOAD(T, AREG, BARR)                                         \
  {                                                                    \
    const float4 xa = *reinterpret_cast<const float4*>(ApA + (T) * 32);\
    const float4 xb = *reinterpret_cast<const float4*>(ApB + (T) * 32);\
    const float4 xc = *reinterpret_cast<const float4*>(bcp + (T) * 32);\
    AREG.x = fmaxf(xa.x + xb.x + xc.x, 0.f);                           \
    AREG.y = fmaxf(xa.y + xb.y + xc.y, 0.f);                           \
    AREG.z = fmaxf(xa.z + xb.z + xc.z, 0.f);                           \
    AREG.w = fmaxf(xa.w + xb.w + xc.w, 0.f);                           \
    _Pragma("unroll") for (int kk = 0; kk < 32; ++kk)                  \
        BARR[kk] = Bp[((T) * 32 + kk) * ldb];                          \
  }

  K2_LOAD(0, aA, bA);
  G_STORE(0, aA);
  __syncthreads();
  for (int t = 0; t < 8; t += 2) {
    K2_LOAD(t + 1, aB, bB);
    G_COMP(0, bA);
    G_STORE(1, aB);
    __syncthreads();
    if (t + 2 < 8) { K2_LOAD(t + 2, aA, bA); }
    G_COMP(1, bB);
    if (t + 2 < 8) { G_STORE(0, aA); }
    __syncthreads();
  }
  if (bn < 128) {
    const float bias = b1[col];
#pragma unroll
    for (int i = 0; i < 4; ++i)
      PT[col * 512 + bm + 4 * ty + i] = acc[i] + bias;
  } else {
#pragma unroll
    for (int i = 0; i < 4; ++i)
      PQGW[(bm + 4 * ty + i) * 768 + col] = acc[i];
  }
#undef K2_LOAD
}

// ---------------------------------------------------------------------------
// K34: 512 blocks; block b owns output row b (b<256: track, else det).
// app reads PT coalesced; E-row in LDS; then out row + row norm.
__global__ __launch_bounds__(256)
void k34_edges_out(const float* __restrict__ PQGW, const float* __restrict__ PT,
                   const float* __restrict__ coords, const float* __restrict__ Wapp2,
                   const float* __restrict__ bapp2, const float* __restrict__ Wg1,
                   const float* __restrict__ bg1, const float* __restrict__ Wg2,
                   const float* __restrict__ bg2, const float* __restrict__ Wa1,
                   const float* __restrict__ ba1, const float* __restrict__ Wa2,
                   const float* __restrict__ ba2, const float* __restrict__ bo,
                   float* __restrict__ outm, float* __restrict__ nrm) {
  __shared__ __align__(16) float2 qw[128];   // {Q[fixed b][j], Wapp2[j]}
  __shared__ __align__(16) float sWg1[256], sWg2[32], sGfix[32];
  __shared__ __align__(16) float sE[256];
  __shared__ float sWa1[16], sBa1[8], sWa2[8], wpart[4];
  const int tid = threadIdx.x;
  const int b = blockIdx.x;
  const bool istrack = (b < 256);
  const int vbase = istrack ? 256 : 0;   // varied node base (src side)

  if (tid < 128) {
    float2 t2;
    t2.x = PQGW[b * 768 + 128 + tid];
    t2.y = Wapp2[tid];
    qw[tid] = t2;
  }
  sWg1[tid] = Wg1[tid];
  if (tid < 32) sWg2[tid] = Wg2[tid];
  if (tid < 16) sWa1[tid] = Wa1[tid];
  if (tid < 8) { sBa1[tid] = ba1[tid]; sWa2[tid] = Wa2[tid]; }
  __syncthreads();
  if (tid < 32) {  // fixed node in DST slot: Wg1 rows 4..7
    float g = bg1[tid];
#pragma unroll
    for (int q = 0; q < 4; ++q)
      g = fmaf(coords[b * 4 + q], sWg1[(4 + q) * 32 + tid], g);
    sGfix[tid] = g;
  }
  __syncthreads();

  const int vr = vbase + tid;  // varied node (src side)
  // app: pre = P[varied] + Q[fixed]; P read from PT -> coalesced across lanes
  const float* __restrict__ ptb = PT + vr;
  float z = 0.f;
#pragma unroll 8
  for (int j = 0; j < 128; ++j) {
    const float2 q2 = qw[j];
    float a = ptb[j * 512] + q2.x;
    a = a > 0.f ? a : 0.f;
    z = fmaf(a, q2.y, z);
  }
  const float app = sigmoidf_(z + bapp2[0]);
  // geo: varied node in SRC slot: Wg1 rows 0..3
  const float4 cp = *reinterpret_cast<const float4*>(coords + vr * 4);
  float gz = 0.f;
#pragma unroll
  for (int m = 0; m < 32; ++m) {
    float hm = sGfix[m];
    hm = fmaf(cp.x, sWg1[0 * 32 + m], hm);
    hm = fmaf(cp.y, sWg1[1 * 32 + m], hm);
    hm = fmaf(cp.z, sWg1[2 * 32 + m], hm);
    hm = fmaf(cp.w, sWg1[3 * 32 + m], hm);
    hm = hm > 0.f ? hm : 0.f;
    gz = fmaf(hm, sWg2[m], gz);
  }
  const float geo = sigmoidf_(gz + bg2[0]);
  float ez = 0.f;
#pragma unroll
  for (int m = 0; m < 8; ++m) {
    float hm = fmaf(app, sWa1[m], fmaf(geo, sWa1[8 + m], sBa1[m]));
    hm = hm > 0.f ? hm : 0.f;
    ez = fmaf(hm, sWa2[m], ez);
  }
  sE[tid] = sigmoidf_(ez + ba2[0]);
  __syncthreads();

  // out row: c = tid. acc = HW1[b][c] + sum_j sE[j] * G[vbase+j][c]
  const int c = tid;
  float a0 = 0.f, a1 = 0.f, a2 = 0.f, a3 = 0.f;
  const float* __restrict__ gcol = PQGW + vbase * 768 + 256 + c;
#pragma unroll 4
  for (int j = 0; j < 256; j += 4) {
    const float4 e4 = *reinterpret_cast<const float4*>(&sE[j]);
    a0 = fmaf(e4.x, gcol[(j + 0) * 768], a0);
    a1 = fmaf(e4.y, gcol[(j + 1) * 768], a1);
    a2 = fmaf(e4.z, gcol[(j + 2) * 768], a2);
    a3 = fmaf(e4.w, gcol[(j + 3) * 768], a3);
  }
  const float base = PQGW[b * 768 + 512 + c] + bo[c];
  float vv = base + ((a0 + a1) + (a2 + a3));
  vv = vv > 0.f ? vv : 0.f;
  outm[b * 256 + c] = vv;
  // row norm
  float nsq = vv * vv;
  nsq = allred16(nsq);
  nsq += swz_get<0x401F>(nsq);          // xor16
  nsq += __shfl_xor(nsq, 32, 64);       // xor32
  if ((tid & 63) == 0) wpart[tid >> 6] = nsq;
  __syncthreads();
  if (tid == 0)
    nrm[b] = fmaxf(sqrtf(wpart[0] + wpart[1] + wpart[2] + wpart[3]), 1e-6f);
}

// ---------------------------------------------------------------------------
// K6: Mblk = exp(5*score(cos, iou)). 64-block GEMM Out_track@Out_det^T with
// inline iou from co + score-MLP epilogue. grid (8,8).
__global__ __launch_bounds__(256)
void k6_score(const float* __restrict__ outm, const float* __restrict__ nrm,
              const float* __restrict__ co, const float* __restrict__ Wf1,
              const float* __restrict__ bf1, const float* __restrict__ Wf2,
              const float* __restrict__ bf2, float* __restrict__ Mblk) {
  __shared__ __align__(16) float Ast[2][32][36];
  const int tid = threadIdx.x;
  const int tx = tid & 31, ty = tid >> 5;
  const int ar = tid >> 3, ac = (tid & 7) * 4;
  const int s0 = blockIdx.y * 32, d0 = blockIdx.x * 32;
  const float* __restrict__ Ap = outm + (s0 + ar) * 256 + ac;
  const float* __restrict__ Bp = outm + (256 + d0 + tx) * 256;  // det row, ldb=1
  float4 aA, aB;
  float bA[32], bB[32];
  float acc[4] = {0.f, 0.f, 0.f, 0.f};

  G_LOAD(0, aA, bA, Ap, Bp, 1);
  G_STORE(0, aA);
  __syncthreads();
  for (int t = 0; t < 8; t += 2) {
    G_LOAD(t + 1, aB, bB, Ap, Bp, 1);
    G_COMP(0, bA);
    G_STORE(1, aB);
    __syncthreads();
    if (t + 2 < 8) { G_LOAD(t + 2, aA, bA, Ap, Bp, 1); }
    G_COMP(1, bB);
    if (t + 2 < 8) { G_STORE(0, aA); }
    __syncthreads();
  }
  const float nb = nrm[256 + d0 + tx];
  const float4 B4 = *reinterpret_cast<const float4*>(co + (256 + d0 + tx) * 4);
  const float areaB = (B4.z - B4.x) * (B4.w - B4.y);
  float w1c[8], w1i[8], w2[8];
#pragma unroll
  for (int m = 0; m < 8; ++m) {
    w1c[m] = Wf1[m]; w1i[m] = Wf1[8 + m]; w2[m] = Wf2[m];
  }
  const float bf20 = bf2[0];
#pragma unroll
  for (int i = 0; i < 4; ++i) {
    const int r = s0 + 4 * ty + i;
    const float4 A4 = *reinterpret_cast<const float4*>(co + r * 4);
    const float ix1 = fmaxf(A4.x, B4.x), iy1 = fmaxf(A4.y, B4.y);
    const float ix2 = fminf(A4.z, B4.z), iy2 = fminf(A4.w, B4.w);
    const float inter = fmaxf(ix2 - ix1, 0.f) * fmaxf(iy2 - iy1, 0.f);
    const float areaA = (A4.z - A4.x) * (A4.w - A4.y);
    const float i1 = inter / (areaA + areaB - inter + 1e-8f);
    const float cosv = acc[i] / (nrm[r] * nb);
    float sz = 0.f;
#pragma unroll
    for (int m = 0; m < 8; ++m) {
      float hm = fmaf(cosv, w1c[m], fmaf(i1, w1i[m], bf1[m]));
      hm = hm > 0.f ? hm : 0.f;
      sz = fmaf(hm, w2[m], sz);
    }
    const float score = sigmoidf_(sz + bf20);
    Mblk[r * 256 + d0 + tx] = expf(5.0f * score);
  }
}

// ---------------------------------------------------------------------------
// K7: Sinkhorn, single 1024-thread block, M register-resident (row fp16).
__global__ __launch_bounds__(1024)
void k7_sink(const float* __restrict__ Mg, float* __restrict__ outp) {
  __shared__ __align__(16) float su_f[256];
  __shared__ __align__(16) float svs_f[256];   // 256*sv
  __shared__ __align__(16) float psum[16][260];
  __shared__ float wsumU[16], wsumV[4];
  const int tid = threadIdx.x, w = tid >> 6, l = tid & 63;
  const float slack = 2.71828182845904523536f;  // exp(LAM*SLACK) = exp(1)
  const float INV256 = 0.00390625f;
  const int rev = ((l & 1) << 3) | ((l & 2) << 1) | ((l & 4) >> 1) | ((l & 8) >> 3);
  const bool b0 = l & 1, b1 = l & 2, b2 = l & 4, b3 = l & 8;

  h2t mrA[16], mrB[16];
#pragma unroll
  for (int i = 0; i < 16; ++i) {
    const float4 f = *reinterpret_cast<const float4*>(Mg + (w * 16 + i) * 256 + 4 * l);
    mrA[i] = pack2(f.x, f.y);
    mrB[i] = pack2(f.z, f.w);
  }
  if (tid < 256) svs_f[tid] = 256.0f;
  __syncthreads();

  float sv256 = 1.0f;
  for (int it = 0; it < 8; ++it) {
    const float sv_tot =
        (it == 0) ? 257.0f : (wsumV[0] + wsumV[1] + wsumV[2] + wsumV[3] + sv256);
    const float su256 = 1.0f / (slack * sv_tot);
    // row pass
    const float4 va = *reinterpret_cast<const float4*>(&svs_f[4 * l]);
    const h2t sva = pack2(va.x, va.y), svb = pack2(va.z, va.w);
    float p[16];
#pragma unroll
    for (int i = 0; i < 16; ++i) p[i] = fdot2f(mrA[i], sva, fdot2f(mrB[i], svb, 0.0f));
#pragma unroll
    for (int i = 0; i < 8; ++i) {
      const float keep = b0 ? p[i + 8] : p[i], give = b0 ? p[i] : p[i + 8];
      p[i] = keep + dpp_get<0xB1>(give);
    }
#pragma unroll
    for (int i = 0; i < 4; ++i) {
      const float keep = b1 ? p[i + 4] : p[i], give = b1 ? p[i] : p[i + 4];
      p[i] = keep + dpp_get<0x4E>(give);
    }
#pragma unroll
    for (int i = 0; i < 2; ++i) {
      const float keep = b2 ? p[i + 2] : p[i], give = b2 ? p[i] : p[i + 2];
      p[i] = keep + dpp_get<0x141>(give);
    }
    {
      const float keep = b3 ? p[1] : p[0], give = b3 ? p[0] : p[1];
      p[0] = keep + dpp_get<0x140>(give);
    }
    float S = p[0];
    S += swz_get<0x401F>(S);
    S += __shfl_xor(S, 32, 64);
    const float su_val = 1.0f / (S * INV256 + slack * sv256);
    if (l < 16) su_f[w * 16 + rev] = su_val;
    const float wsU = allred16(su_val);
    if (l == 0) wsumU[w] = wsU;
    asm volatile("s_waitcnt lgkmcnt(0)" ::: "memory");  // same-wave su_f readback
    // col partials from row regs
    float su16[16];
#pragma unroll
    for (int k = 0; k < 16; k += 4) {
      const float4 t = *reinterpret_cast<const float4*>(&su_f[w * 16 + k]);
      su16[k] = t.x; su16[k + 1] = t.y; su16[k + 2] = t.z; su16[k + 3] = t.w;
    }
    float pc0 = 0.f, pc1 = 0.f, pc2 = 0.f, pc3 = 0.f;
#pragma unroll
    for (int i = 0; i < 16; ++i) {
      const float ui = su16[i];
      pc0 = fmaf((float)mrA[i].x, ui, pc0);
      pc1 = fmaf((float)mrA[i].y, ui, pc1);
      pc2 = fmaf((float)mrB[i].x, ui, pc2);
      pc3 = fmaf((float)mrB[i].y, ui, pc3);
    }
    float4 pcv; pcv.x = pc0; pcv.y = pc1; pcv.z = pc2; pcv.w = pc3;
    *reinterpret_cast<float4*>(&psum[w][4 * l]) = pcv;
    __syncthreads();
    // sv phase
    const float su_tot = wsumU[0] + wsumU[1] + wsumU[2] + wsumU[3] + wsumU[4] +
                         wsumU[5] + wsumU[6] + wsumU[7] + wsumU[8] + wsumU[9] +
                         wsumU[10] + wsumU[11] + wsumU[12] + wsumU[13] +
                         wsumU[14] + wsumU[15] + su256;
    if (tid < 256) {
      float cs = 0.f;
#pragma unroll
      for (int g = 0; g < 16; ++g) cs += psum[g][tid];
      const float sv_val = 1.0f / (cs + slack * su256);
      svs_f[tid] = 256.0f * sv_val;
      float t = allred16(sv_val);
      t += swz_get<0x401F>(t);
      t += __shfl_xor(t, 32, 64);
      if (l == 0) wsumV[w] = t;
    }
    sv256 = 1.0f / (slack * su_tot);
    __syncthreads();
  }
  const float4 sv4 = *reinterpret_cast<const float4*>(&svs_f[4 * l]);
#pragma unroll
  for (int i = 0; i < 16; ++i) {
    const float uo = su_f[w * 16 + i] * INV256;
    float4 o;
    o.x = uo * (float)mrA[i].x * sv4.x;
    o.y = uo * (float)mrA[i].y * sv4.y;
    o.z = uo * (float)mrB[i].x * sv4.z;
    o.w = uo * (float)mrB[i].y * sv4.w;
    *reinterpret_cast<float4*>(outp + (w * 16 + i) * 256 + 4 * l) = o;
  }
}

// ---------------------------------------------------------------------------
extern "C" void kernel_launch(void* const* d_in, const int* in_sizes, int n_in,
                              void* d_out, int out_size, void* d_ws, size_t ws_size,
                              hipStream_t stream) {
  (void)in_sizes; (void)n_in; (void)out_size; (void)ws_size;
  const float* x      = (const float*)d_in[0];
  const float* coords = (const float*)d_in[1];
  const float* co     = (const float*)d_in[2];
  // d_in[3] = edge_index (int32) — structure is deterministic, not needed
  const float* Wc    = (const float*)d_in[4];
  const float* bc    = (const float*)d_in[5];
  const float* Wapp1 = (const float*)d_in[6];
  const float* bapp1 = (const float*)d_in[7];
  const float* Wapp2 = (const float*)d_in[8];
  const float* bapp2 = (const float*)d_in[9];
  const float* Wg1   = (const float*)d_in[10];
  const float* bg1   = (const float*)d_in[11];
  const float* Wg2   = (const float*)d_in[12];
  const float* bg2   = (const float*)d_in[13];
  const float* Wa1   = (const float*)d_in[14];
  const float* ba1   = (const float*)d_in[15];
  const float* Wa2   = (const float*)d_in[16];
  const float* ba2   = (const float*)d_in[17];
  const float* Wo1   = (const float*)d_in[18];
  const float* Wo2   = (const float*)d_in[19];
  const float* bo    = (const float*)d_in[20];
  const float* Wf1   = (const float*)d_in[21];
  const float* bf1   = (const float*)d_in[22];
  const float* Wf2   = (const float*)d_in[23];
  const float* bf2   = (const float*)d_in[24];

  float* ws   = (float*)d_ws;
  float* hAB  = ws + 0;        // 2 * 512*256
  float* PQGW = ws + 262144;   // 512*768 (cols 0..127 unused)
  float* PT   = ws + 655360;   // 128*512 (P transposed, +bapp1)
  float* outm = ws + 720896;   // 512*256
  float* nrm  = ws + 851968;   // 512
  float* Mblk = ws + 852480;   // 256*256

  k1_h<<<dim3(8, 16, 2), 256, 0, stream>>>(x, Wc, hAB);
  k2_pqgw<<<dim3(24, 16), 256, 0, stream>>>(hAB, bc, Wapp1, bapp1, Wo2, Wo1,
                                            PQGW, PT);
  k34_edges_out<<<512, 256, 0, stream>>>(PQGW, PT, coords, Wapp2, bapp2, Wg1,
                                         bg1, Wg2, bg2, Wa1, ba1, Wa2, ba2, bo,
                                         outm, nrm);
  k6_score<<<dim3(8, 8), 256, 0, stream>>>(outm, nrm, co, Wf1, bf1, Wf2, bf2,
                                           Mblk);
  k7_sink<<<1, 1024, 0, stream>>>(Mblk, (float*)d_out);
}